// Round 5
// baseline (539091.553 us; speedup 1.0000x reference)
//
#include <hip/hip_runtime.h>
#include <hip/hip_fp16.h>
#include <math.h>

#define Hn 1024
#define Bn 4096
#define INW 33
#define OUTS (Bn * Hn)
#define TPB 512
#define ROWP 1024   // packets per exchange row: [h0 half (512) | h1 half (512)]
#define NRING 8     // fast-ring slots (self-chain skew <= 1, 8 gives margin)
#define BAILOUT (1 << 20)   // ~0.3 s; then wave goes dead (accept-anything) so
                            // a broken protocol finishes fast as passed:false
                            // instead of wedging the GPU into a watchdog kill

typedef _Float16 half2v __attribute__((ext_vector_type(2)));
typedef unsigned uint4v __attribute__((ext_vector_type(4)));

__device__ __forceinline__ float sigmoidf_(float x) {
    return 1.0f / (1.0f + __expf(-x));
}
__device__ __forceinline__ float tanhf_(float x) {
    float e = __expf(-2.0f * fabsf(x));
    float r = (1.0f - e) / (1.0f + e);
    return copysignf(r, x);
}
__device__ __forceinline__ unsigned pack2(float a, float b) {
    __half2 h = __floats2half2_rn(a, b);
    return __builtin_bit_cast(unsigned, h);
}
__device__ __forceinline__ float dot2acc(unsigned w, unsigned hv, float acc) {
#if __has_builtin(__builtin_amdgcn_fdot2)
    return __builtin_amdgcn_fdot2(__builtin_bit_cast(half2v, w),
                                  __builtin_bit_cast(half2v, hv), acc, false);
#else
    __half2 wh = __builtin_bit_cast(__half2, w);
    __half2 hh = __builtin_bit_cast(__half2, hh);
    float2 wf = __half22float2(wh), hf = __half22float2(hh);
    return acc + wf.x * hf.x + wf.y * hf.y;
#endif
}

// ============ two-tier exchange (R11) ============
// Device-scope (sc0 sc1) round trips go through the die-level coherence
// point (~1 us store->observe). h0 self-exchange involves ONLY the 32 L0
// blocks; h1 ONLY the 64 L1 blocks. If a group is co-located on one XCD,
// sc0-only ops give same-XCD L2 visibility at ~200 cy. Placement is
// undefined architecturally -> treated as a pure PERF variable:
//   - producers publish every row to BOTH a small sc0 fast ring and the
//     coherent buffer (exact R9 path);
//   - consumers dual-poll; a fast hit switches the wave to a pure-fast
//     loop ("learned"), with an unlearn escape for stale-line pathologies.
// Tag-consistency makes this placement-safe: tag+payload share one
// atomically-loaded 8 B packet, each (slot,tag) is written once, stale
// lines carry old tags -> never a false positive; worst case = R9 behavior.
// mode: 0 = dual-poll, 1 = learned-fast, 2 = dead (accept-anything after
// BAILOUT rounds: broken protocol -> fast passed:false, not a wedged GPU).

// L0 dual/learned slice spin.
__device__ __forceinline__ unsigned spin_l0(const unsigned long long* fa,
                                            const unsigned long long* ca,
                                            int lane, unsigned tag, int& mode) {
    unsigned long long vf, vc;
    int rounds = 0;
    if (mode == 2) {                             // dead: single read, accept
        asm volatile("global_load_dwordx2 %0, %1, off sc0 sc1\n\t"
                     "s_waitcnt vmcnt(0)"
                     : "=v"(vc) : "v"(ca + lane) : "memory");
        return (unsigned)vc;
    }
    if (mode == 1) {                             // learned: fast-only rounds
        for (;;) {
            asm volatile("global_load_dwordx2 %0, %1, off sc0\n\t"
                         "s_waitcnt vmcnt(0)"
                         : "=v"(vf) : "v"(fa + lane) : "memory");
            if (__all((unsigned)(vf >> 32) == tag)) return (unsigned)vf;
            if (++rounds > 1024) { mode = 0; break; }   // unlearn escape
        }
        rounds = 0;
    }
    for (;;) {                                   // dual poll
        asm volatile("global_load_dwordx2 %0, %2, off sc0\n\t"
                     "global_load_dwordx2 %1, %3, off sc0 sc1\n\t"
                     "s_waitcnt vmcnt(0)"
                     : "=v"(vf), "=v"(vc)
                     : "v"(fa + lane), "v"(ca + lane) : "memory");
        if (__all((unsigned)(vf >> 32) == tag)) { mode = 1; return (unsigned)vf; }
        if (__all((unsigned)(vc >> 32) == tag)) return (unsigned)vc;
        if (++rounds > BAILOUT) { mode = 2; return (unsigned)vc; }
    }
}

// L1 joint spin: h0 slice always coherent (cross-XCD by design); h1 slice
// dual/learned. Single exit when both slices current (monotone tags).
__device__ __forceinline__ void spin_l1(const unsigned long long* faH1,
                                        const unsigned long long* caH0,
                                        const unsigned long long* caH1,
                                        int lane, unsigned tag,
                                        unsigned& dH0, unsigned& dH1, int& mode) {
    unsigned long long vf, v0, v1;
    int rounds = 0;
    if (mode == 2) {                             // dead: single read, accept
        asm volatile("global_load_dwordx2 %0, %2, off sc0 sc1\n\t"
                     "global_load_dwordx2 %1, %3, off sc0 sc1\n\t"
                     "s_waitcnt vmcnt(0)"
                     : "=v"(v0), "=v"(v1)
                     : "v"(caH0 + lane), "v"(caH1 + lane) : "memory");
        dH0 = (unsigned)v0; dH1 = (unsigned)v1;
        return;
    }
    if (mode == 1) {                             // learned: h1 fast + h0 coh
        for (;;) {
            asm volatile("global_load_dwordx2 %0, %2, off sc0\n\t"
                         "global_load_dwordx2 %1, %3, off sc0 sc1\n\t"
                         "s_waitcnt vmcnt(0)"
                         : "=v"(vf), "=v"(v0)
                         : "v"(faH1 + lane), "v"(caH0 + lane) : "memory");
            bool ok = ((unsigned)(vf >> 32) == tag) & ((unsigned)(v0 >> 32) == tag);
            if (__all(ok)) { dH0 = (unsigned)v0; dH1 = (unsigned)vf; return; }
            if (++rounds > 1024) { mode = 0; break; }   // unlearn escape
        }
        rounds = 0;
    }
    for (;;) {                                   // dual poll
        asm volatile("global_load_dwordx2 %0, %3, off sc0\n\t"
                     "global_load_dwordx2 %1, %4, off sc0 sc1\n\t"
                     "global_load_dwordx2 %2, %5, off sc0 sc1\n\t"
                     "s_waitcnt vmcnt(0)"
                     : "=v"(vf), "=v"(v0), "=v"(v1)
                     : "v"(faH1 + lane), "v"(caH0 + lane), "v"(caH1 + lane)
                     : "memory");
        bool ok0 = ((unsigned)(v0 >> 32) == tag);
        bool okf = ((unsigned)(vf >> 32) == tag);
        bool okc = ((unsigned)(v1 >> 32) == tag);
        if (__all(ok0 & okf)) { dH0 = (unsigned)v0; dH1 = (unsigned)vf; mode = 1; return; }
        if (__all(ok0 & okc)) { dH0 = (unsigned)v0; dH1 = (unsigned)v1; return; }
        if (++rounds > BAILOUT) { mode = 2; dH0 = (unsigned)v0; dH1 = (unsigned)v1; return; }
    }
}

__device__ __forceinline__ void store16_coherent(void* dst, uint4v v) {
    asm volatile("global_store_dwordx4 %0, %1, off sc0 sc1"
                 :: "v"(dst), "v"(v) : "memory");
}
__device__ __forceinline__ void store16_fast(void* dst, uint4v v) {
    asm volatile("global_store_dwordx4 %0, %1, off sc0"
                 :: "v"(dst), "v"(v) : "memory");
}

// xin = [x | ip_emb[ip] | port_emb[port]]  (4096 x 33)
__global__ void prep_kernel(const float* __restrict__ x, const int* __restrict__ ip,
                            const int* __restrict__ port, const float* __restrict__ ip_emb,
                            const float* __restrict__ port_emb, float* __restrict__ xin) {
    int gid = blockIdx.x * blockDim.x + threadIdx.x;
    if (gid < Bn * INW) {
        int t = gid / INW;
        int k = gid - t * INW;
        float v;
        if (k < 17) {
            v = x[t * 17 + k];
        } else if (k < 25) {
            v = ip_emb[ip[t * 8 + (k - 17)]];
        } else {
            int kk = k - 25;
            v = port_emb[port[t * 2 + (kk >> 2)] * 4 + (kk & 3)];
        }
        xin[gid] = v;
    }
}

// Skewed supersteps (R7): row s holds [h0[s] | h1[s-1]], packets tagged s+1.
// R9: slice-spin, 2 barriers, double-buffered LDS, cohesive publish bursts
// (R10 LESSON: publish cohesion dominates barrier cost).
// R11/R12: grid 512, static role map assuming round-robin bx->XCD dispatch
// (bx%8==0 -> 32 L0 blocks on one XCD; bx%8==1 -> 64 L1 blocks = exactly one
// XCD at 2 blocks/CU); non-role blocks exit. Two-tier exchange above.
// R12 POST-MORTEM (fixed here): FAILED absmax 3.5e-2, cf garbage ~468, fast
// completion. Theory: R9 sat at VGPR=128 by allocator CHOICE (launch_bounds
// (512,2) only contracts 1 block/CU); R12's extra spin state pushed past 128
// -> 1 block/CU -> only 256 of 512 blocks resident -> resident role blocks
// spin on producers that are never dispatched -> BAILOUT -> dead mode ->
// tag-valid garbage cascades (f~1 accumulation explains |cf|~468).
// R13 FIX: __launch_bounds__(TPB, 4) contracts 4 waves/EU = 16 waves/CU =
// 2 blocks/CU -> all 512 blocks co-resident BY CONTRACT (compiler must fit
// 128 VGPRs, spilling if needed; spills show as slow-but-passing).
__global__ void __launch_bounds__(TPB, 4) lstm_kernel(
    const float* __restrict__ xin,
    const float* __restrict__ hid0, const float* __restrict__ cel0,
    const float* __restrict__ Wih0, const float* __restrict__ Whh0,
    const float* __restrict__ bih0, const float* __restrict__ bhh0,
    const float* __restrict__ Wih1, const float* __restrict__ Whh1,
    const float* __restrict__ bih1, const float* __restrict__ bhh1,
    float* __restrict__ out,
    unsigned long long* __restrict__ rowpkt,   // [Bn+1][ROWP] coherent
    unsigned long long* __restrict__ ringH0,   // [NRING][512] fast (sc0)
    unsigned long long* __restrict__ ringH1,   // [NRING][512] fast (sc0)
    int use_fast)
{
    __shared__ unsigned hs2[2][1024];          // double-buffered half2 h chunks
    __shared__ unsigned long long stg[16];     // outgoing packet staging
    const int tid  = threadIdx.x;
    const int lane = tid & 63;
    const int wave = tid >> 6;                 // 0..7
    const int bx   = blockIdx.x;

    // ---- static role map (perf-only placement guess; correctness-neutral) ----
    const int bm = bx & 7;
    if (bm == 0 && bx < 256) {
        // ========== layer 0 : 32 blocks (roles 0..31), wave owns 4 h-idx ====
        const int role = bx >> 3;
        const int j0 = role * 32 + wave * 4;
        unsigned w2[4][4][8];     // f16-pair weights of Whh0
        float    wx[4][4];        // fp32 x-weights (lane < 33)
        float    bs[4][4];
#pragma unroll
        for (int jj = 0; jj < 4; ++jj) {
#pragma unroll
            for (int g = 0; g < 4; ++g) {
                const int row = g * Hn + (j0 + jj);
                const float* wr = Whh0 + (size_t)row * Hn;
#pragma unroll
                for (int k = 0; k < 8; ++k) {
                    int c = lane + 64 * k;
                    w2[jj][g][k] = pack2(wr[2 * c], wr[2 * c + 1]);
                }
                wx[jj][g] = (lane < INW) ? Wih0[row * INW + lane] : 0.0f;
                bs[jj][g] = bih0[row] + bhh0[row];
            }
        }
        float cst[4], hcur[4];
#pragma unroll
        for (int jj = 0; jj < 4; ++jj) { cst[jj] = cel0[j0 + jj]; hcur[jj] = 0.0f; }

        int mode = 0;    // per-wave fast-path learning state
        for (int s = 0; s < Bn; ++s) {
            const int b = s & 1;
            float xv = xin[s * INW + (lane < INW ? lane : 0)];  // prefetch (L2-hot)
            if (s == 0) {
                int q = wave * 64 + lane;
                hs2[0][q] = pack2(hid0[2 * q], hid0[2 * q + 1]);
            } else {
                const unsigned long long* ca = rowpkt + (size_t)(s - 1) * ROWP + wave * 64;
                const unsigned long long* fa = use_fast
                    ? ringH0 + (size_t)((s - 1) & (NRING - 1)) * 512 + wave * 64
                    : ca;
                unsigned d = spin_l0(fa, ca, lane, (unsigned)s, mode);
                hs2[b][wave * 64 + lane] = d;
            }
            __syncthreads();                   // barrier A: hs2[b] ready

            float acc[4][4];
#pragma unroll
            for (int jj = 0; jj < 4; ++jj)
#pragma unroll
                for (int g = 0; g < 4; ++g) acc[jj][g] = wx[jj][g] * xv;
#pragma unroll
            for (int k = 0; k < 8; ++k) {
                unsigned hv = hs2[b][lane + 64 * k];   // 2-way bank alias: free
#pragma unroll
                for (int jj = 0; jj < 4; ++jj)
#pragma unroll
                    for (int g = 0; g < 4; ++g)
                        acc[jj][g] = dot2acc(w2[jj][g][k], hv, acc[jj][g]);
            }

#pragma unroll
            for (int off = 32; off >= 1; off >>= 1)
#pragma unroll
                for (int jj = 0; jj < 4; ++jj)
#pragma unroll
                    for (int g = 0; g < 4; ++g)
                        acc[jj][g] += __shfl_xor(acc[jj][g], off);

#pragma unroll
            for (int jj = 0; jj < 4; ++jj) {
                float gi = sigmoidf_(acc[jj][0] + bs[jj][0]);
                float gf = sigmoidf_(acc[jj][1] + bs[jj][1]);
                float gg = tanhf_   (acc[jj][2] + bs[jj][2]);
                float go = sigmoidf_(acc[jj][3] + bs[jj][3]);
                cst[jj] = gf * cst[jj] + gi * gg;
                hcur[jj] = go * tanhf_(cst[jj]);
            }
            // stage 2 packets per wave; wave 0 bursts the block's 128 B segment
            if (lane == 0) {
                unsigned long long tw = ((unsigned long long)(s + 1)) << 32;
                stg[2 * wave]     = tw | pack2(hcur[0], hcur[1]);
                stg[2 * wave + 1] = tw | pack2(hcur[2], hcur[3]);
            }
            __syncthreads();                   // barrier B: stg ready; hs2 reads done
            if (wave == 0 && lane < 8) {
                uint4v v = *(const uint4v*)&stg[2 * lane];
                if (use_fast) {
                    char* fdst = (char*)(ringH0 + (size_t)(s & (NRING - 1)) * 512)
                               + role * 128 + lane * 16;
                    store16_fast(fdst, v);     // fast first: on the hot chain
                }
                char* cdst = (char*)(rowpkt + (size_t)s * ROWP) + role * 128 + lane * 16;
                store16_coherent(cdst, v);
            }
        }
        if (lane == 0) {
#pragma unroll
            for (int jj = 0; jj < 4; ++jj) {
                out[OUTS + j0 + jj] = hcur[jj];            // hf layer 0
                out[OUTS + 2 * Hn + j0 + jj] = cst[jj];    // cf layer 0
            }
        }
    } else if (bm == 1) {
        // ========== layer 1 : 64 blocks (roles 0..63), wave owns 2 h-idx ====
        const int role = bx >> 3;
        const int j0  = role * 16 + wave * 2;
        unsigned w2[2][4][16];    // k<8: Wih1 (vs h0[t]) ; k>=8: Whh1 (vs h1[t-1])
        float    bs[2][4];
#pragma unroll
        for (int jj = 0; jj < 2; ++jj) {
#pragma unroll
            for (int g = 0; g < 4; ++g) {
                const int row = g * Hn + (j0 + jj);
                const float* wr1 = Wih1 + (size_t)row * Hn;
                const float* wr2 = Whh1 + (size_t)row * Hn;
#pragma unroll
                for (int k = 0; k < 8; ++k) {
                    int c = lane + 64 * k;
                    w2[jj][g][k]     = pack2(wr1[2 * c], wr1[2 * c + 1]);
                    w2[jj][g][8 + k] = pack2(wr2[2 * c], wr2[2 * c + 1]);
                }
                bs[jj][g] = bih1[row] + bhh1[row];
            }
        }
        float cst[2], hcur[2];
#pragma unroll
        for (int jj = 0; jj < 2; ++jj) { cst[jj] = cel0[Hn + j0 + jj]; hcur[jj] = 0.0f; }

        // publish initial h1 into row 0's h1 half (tag 1), both tiers
        if (wave == 0 && lane < 4) {
            int base = Hn + role * 16 + 4 * lane;
            uint4v v;
            v.x = pack2(hid0[base],     hid0[base + 1]);  v.y = 1u;
            v.z = pack2(hid0[base + 2], hid0[base + 3]);  v.w = 1u;
            if (use_fast) {
                char* fdst = (char*)ringH1 + role * 64 + lane * 16;   // slot 0
                store16_fast(fdst, v);
            }
            char* dst = (char*)(rowpkt + 512) + role * 64 + lane * 16;
            store16_coherent(dst, v);
        }

        int mode = 0;    // per-wave fast-path learning state (h1 slice)
        for (int s = 1; s <= Bn; ++s) {
            const int t = s - 1;               // LSTM step this superstep computes
            const int b = s & 1;
            const unsigned long long* rb = rowpkt + (size_t)(s - 1) * ROWP;
            const unsigned long long* caH0 = rb + wave * 64;
            const unsigned long long* caH1 = rb + 512 + wave * 64;
            const unsigned long long* faH1 = use_fast
                ? ringH1 + (size_t)((s - 1) & (NRING - 1)) * 512 + wave * 64
                : caH1;
            unsigned dA, dB;
            spin_l1(faH1, caH0, caH1, lane, (unsigned)s, dA, dB, mode);
            hs2[b][wave * 64 + lane]       = dA;   // h0[t] chunk
            hs2[b][512 + wave * 64 + lane] = dB;   // h1[t-1] chunk
            __syncthreads();                   // barrier A: hs2[b] ready

            float acc[2][4];
#pragma unroll
            for (int jj = 0; jj < 2; ++jj)
#pragma unroll
                for (int g = 0; g < 4; ++g) acc[jj][g] = 0.0f;
#pragma unroll
            for (int k = 0; k < 16; ++k) {
                unsigned hv = hs2[b][lane + 64 * k];
#pragma unroll
                for (int jj = 0; jj < 2; ++jj)
#pragma unroll
                    for (int g = 0; g < 4; ++g)
                        acc[jj][g] = dot2acc(w2[jj][g][k], hv, acc[jj][g]);
            }

#pragma unroll
            for (int off = 32; off >= 1; off >>= 1)
#pragma unroll
                for (int jj = 0; jj < 2; ++jj)
#pragma unroll
                    for (int g = 0; g < 4; ++g)
                        acc[jj][g] += __shfl_xor(acc[jj][g], off);

#pragma unroll
            for (int jj = 0; jj < 2; ++jj) {
                float gi = sigmoidf_(acc[jj][0] + bs[jj][0]);
                float gf = sigmoidf_(acc[jj][1] + bs[jj][1]);
                float gg = tanhf_   (acc[jj][2] + bs[jj][2]);
                float go = sigmoidf_(acc[jj][3] + bs[jj][3]);
                cst[jj] = gf * cst[jj] + gi * gg;
                hcur[jj] = go * tanhf_(cst[jj]);
            }
            if (lane == 0) {
                unsigned long long tw = ((unsigned long long)(s + 1)) << 32;
                stg[wave] = tw | pack2(hcur[0], hcur[1]);
                float2 o2 = make_float2(fmaxf(hcur[0], 0.0f), fmaxf(hcur[1], 0.0f));
                *(float2*)(out + (size_t)t * Hn + j0) = o2;   // outputs[t] = relu(h1)
            }
            __syncthreads();                   // barrier B: stg ready; hs2 reads done
            if (wave == 0 && lane < 4) {
                uint4v v = *(const uint4v*)&stg[2 * lane];
                if (use_fast) {
                    char* fdst = (char*)(ringH1 + (size_t)(s & (NRING - 1)) * 512)
                               + role * 64 + lane * 16;
                    store16_fast(fdst, v);
                }
                char* dst = (char*)(rowpkt + (size_t)s * ROWP + 512) + role * 64 + lane * 16;
                store16_coherent(dst, v);      // h1[t] into row s's h1 half
            }
        }
        if (lane == 0) {
#pragma unroll
            for (int jj = 0; jj < 2; ++jj) {
                out[OUTS + Hn + j0 + jj] = hcur[jj];           // hf layer 1
                out[OUTS + 3 * Hn + j0 + jj] = cst[jj];        // cf layer 1
            }
        }
    }
    // all other blocks: no role, exit immediately (free their CU slot)
}

extern "C" void kernel_launch(void* const* d_in, const int* in_sizes, int n_in,
                              void* d_out, int out_size, void* d_ws, size_t ws_size,
                              hipStream_t stream) {
    const float* x        = (const float*)d_in[0];
    const int*   ip       = (const int*)d_in[1];
    const int*   port     = (const int*)d_in[2];
    const float* hidden   = (const float*)d_in[3];
    const float* cell     = (const float*)d_in[4];
    const float* ip_emb   = (const float*)d_in[5];
    const float* port_emb = (const float*)d_in[6];
    const float* Wih0     = (const float*)d_in[7];
    const float* Whh0     = (const float*)d_in[8];
    const float* bih0     = (const float*)d_in[9];
    const float* bhh0     = (const float*)d_in[10];
    const float* Wih1     = (const float*)d_in[11];
    const float* Whh1     = (const float*)d_in[12];
    const float* bih1     = (const float*)d_in[13];
    const float* bhh1     = (const float*)d_in[14];
    float* out = (float*)d_out;

    // ws layout: rowpkt ((Bn+1) x 1024 u64 = 33.6 MB) | xin (4096x33 f32)
    // | fast rings (2 x NRING x 512 u64 = 64 KB, only if ws has room).
    // Tags are s+1 in the high 32 bits; 0xAA poison never matches -> no
    // zeroing pass needed (rings rely on the same property).
    unsigned long long* rowpkt = (unsigned long long*)d_ws;
    float* xin = (float*)(rowpkt + (size_t)(Bn + 1) * ROWP);
    size_t used = (size_t)(Bn + 1) * ROWP * 8 + (size_t)Bn * INW * 4;
    size_t ring_off = (used + 255) & ~(size_t)255;
    int use_fast = 0;
    unsigned long long* ringH0 = rowpkt;   // dummy (never dereferenced if !use_fast)
    unsigned long long* ringH1 = rowpkt;
    if (ws_size >= ring_off + 2 * (size_t)NRING * 512 * 8 + 256) {
        use_fast = 1;
        ringH0 = (unsigned long long*)((char*)d_ws + ring_off);
        ringH1 = ringH0 + (size_t)NRING * 512;
    }

    prep_kernel<<<dim3((Bn * INW + 255) / 256), dim3(256), 0, stream>>>(
        x, ip, port, ip_emb, port_emb, xin);

    lstm_kernel<<<dim3(512), dim3(TPB), 0, stream>>>(
        xin, hidden, cell, Wih0, Whh0, bih0, bhh0, Wih1, Whh1, bih1, bhh1,
        out, rowpkt, ringH0, ringH1, use_fast);
}

// Round 6
// 32335.455 us; speedup vs baseline: 16.6718x; 16.6718x over previous
//
#include <hip/hip_runtime.h>
#include <hip/hip_fp16.h>
#include <math.h>

#define Hn 1024
#define Bn 4096
#define INW 33
#define OUTS (Bn * Hn)
#define TPB 512
#define ROWU 1024          // u32 per exchange row: [h0 half2 x512 | h1 half2 x512]
#define FLAGSTRIDE 16      // u32 per row-flag record (64 B line isolation)
#define BAILOUT (1 << 20)  // ~0.3 s; then give up the wait so a broken protocol
                           // finishes fast as passed:false, not a wedged GPU

typedef _Float16 half2v __attribute__((ext_vector_type(2)));
typedef unsigned uint4v __attribute__((ext_vector_type(4)));

__device__ __forceinline__ float sigmoidf_(float x) {
    return 1.0f / (1.0f + __expf(-x));
}
__device__ __forceinline__ float tanhf_(float x) {
    float e = __expf(-2.0f * fabsf(x));
    float r = (1.0f - e) / (1.0f + e);
    return copysignf(r, x);
}
__device__ __forceinline__ unsigned pack2(float a, float b) {
    __half2 h = __floats2half2_rn(a, b);
    return __builtin_bit_cast(unsigned, h);
}
__device__ __forceinline__ float dot2acc(unsigned w, unsigned hv, float acc) {
#if __has_builtin(__builtin_amdgcn_fdot2)
    return __builtin_amdgcn_fdot2(__builtin_bit_cast(half2v, w),
                                  __builtin_bit_cast(half2v, hv), acc, false);
#else
    __half2 wh = __builtin_bit_cast(__half2, w);
    __half2 hh = __builtin_bit_cast(__half2, hv);
    float2 wf = __half22float2(wh), hf = __half22float2(hh);
    return acc + wf.x * hf.x + wf.y * hf.y;
#endif
}

// ============ R14: flag-gated tagless exchange ============
// R9's slice-spin had every one of 96 blocks x 512 lanes issuing an 8 B
// coherent load per poll round (~50K requests in flight hammering the
// coherence point); FETCH showed ~9 HBM-visible rounds per step -> ~3.5 us
// of the 4.15 us step is the exchange. R13 killed the XCD-placement bet
// (weight-resident waves need >128 unified VGPRs -> 2 blocks/CU impossible
// -> L1 can never be XCD-local). This round separates DETECTION from DATA:
//   - producers do their cohesive burst (sc0 sc1), s_waitcnt vmcnt(0) so the
//     stores are globally complete, then ONE global_atomic_add on the row's
//     flag (atomics execute at the coherence point, device scope, m20);
//   - consumers poll the flag with all-64-lanes-same-address loads (one
//     coalesced request per wave per round -> poll traffic drops ~500x),
//     then bulk-read the row ONCE. Ordering: stores complete before the inc
//     is issued; a load issued after the flag read observed the final count
//     must see the data at the coherence point.
// Tags are gone -> rows are pure half2 payload (4 KB vs 8 KB). Flags are
// hipMemsetAsync-zeroed each launch (stream memset is graph-capture-safe).
// Grid 96, launch_bounds(TPB,2): robust to ANY VGPR tier (no co-residency
// cliff -- the R12 lesson).

// Poll a u32 flag until ==target. All lanes load the same address (single
// coalesced request per wave). Uniform result -> uniform branch.
__device__ __forceinline__ void poll_flag32(const unsigned* fp, unsigned target) {
    unsigned c;
    int rounds = 0;
    for (;;) {
        asm volatile("global_load_dword %0, %1, off sc0 sc1\n\t"
                     "s_waitcnt vmcnt(0)"
                     : "=v"(c) : "v"(fp) : "memory");
        if (c == target) break;
        if (++rounds > BAILOUT) break;   // wrong answer beats a wedged GPU
    }
}
// Poll a u64 (two u32 counters) until ==target.
__device__ __forceinline__ void poll_flag64(const unsigned long long* fp,
                                            unsigned long long target) {
    unsigned long long c;
    int rounds = 0;
    for (;;) {
        asm volatile("global_load_dwordx2 %0, %1, off sc0 sc1\n\t"
                     "s_waitcnt vmcnt(0)"
                     : "=v"(c) : "v"(fp) : "memory");
        if (c == target) break;
        if (++rounds > BAILOUT) break;
    }
}

__device__ __forceinline__ unsigned load4_coherent(const unsigned* p) {
    unsigned d;
    asm volatile("global_load_dword %0, %1, off sc0 sc1\n\t"
                 "s_waitcnt vmcnt(0)"
                 : "=v"(d) : "v"(p) : "memory");
    return d;
}
__device__ __forceinline__ unsigned long long load8_coherent(const unsigned long long* p) {
    unsigned long long d;
    asm volatile("global_load_dwordx2 %0, %1, off sc0 sc1\n\t"
                 "s_waitcnt vmcnt(0)"
                 : "=v"(d) : "v"(p) : "memory");
    return d;
}
__device__ __forceinline__ void store16_coherent(void* dst, uint4v v) {
    asm volatile("global_store_dwordx4 %0, %1, off sc0 sc1"
                 :: "v"(dst), "v"(v) : "memory");
}
__device__ __forceinline__ void wait_stores() {
    asm volatile("s_waitcnt vmcnt(0)" ::: "memory");
}

// xin = [x | ip_emb[ip] | port_emb[port]]  (4096 x 33)
__global__ void prep_kernel(const float* __restrict__ x, const int* __restrict__ ip,
                            const int* __restrict__ port, const float* __restrict__ ip_emb,
                            const float* __restrict__ port_emb, float* __restrict__ xin) {
    int gid = blockIdx.x * blockDim.x + threadIdx.x;
    if (gid < Bn * INW) {
        int t = gid / INW;
        int k = gid - t * INW;
        float v;
        if (k < 17) {
            v = x[t * 17 + k];
        } else if (k < 25) {
            v = ip_emb[ip[t * 8 + (k - 17)]];
        } else {
            int kk = k - 25;
            v = port_emb[port[t * 2 + (kk >> 2)] * 4 + (kk & 3)];
        }
        xin[gid] = v;
    }
}

// Skewed supersteps (R7): row s holds [h0[s] | h1[s-1]]. Superstep s: L0
// computes step s from row s-1's h0 half; L1 computes step s-1 from both
// halves of row s-1. flag[s] = {h0cnt (32 producers), h1cnt (64 producers)}.
// R9 lessons kept: cohesive publish bursts via LDS staging + barrier
// (R10: scattered partial-line coherent stores = 2.4x write amplification),
// double-buffered hs2, 512-thr blocks (R8: 1024-thr caps VGPR at 64).
// R13 lessons: weight-resident design needs >128 unified regs -> 1 block/CU
// is the only safe tier -> grid 96; never force occupancy via launch_bounds.
__global__ void __launch_bounds__(TPB, 2) lstm_kernel(
    const float* __restrict__ xin,
    const float* __restrict__ hid0, const float* __restrict__ cel0,
    const float* __restrict__ Wih0, const float* __restrict__ Whh0,
    const float* __restrict__ bih0, const float* __restrict__ bhh0,
    const float* __restrict__ Wih1, const float* __restrict__ Whh1,
    const float* __restrict__ bih1, const float* __restrict__ bhh1,
    float* __restrict__ out,
    unsigned* __restrict__ hx,       // [Bn+1][ROWU] exchange rows (pure half2)
    unsigned* __restrict__ flags)    // [Bn+1][FLAGSTRIDE] {h0cnt,h1cnt,pad}
{
    __shared__ unsigned hs2[2][1024];          // double-buffered half2 h chunks
    __shared__ unsigned stg[16];               // outgoing publish staging (u32)
    const int tid  = threadIdx.x;
    const int lane = tid & 63;
    const int wave = tid >> 6;                 // 0..7
    const int bx   = blockIdx.x;

    if (bx < 32) {
        // ========== layer 0 : 32 blocks, wave owns 4 h-indices ==========
        const int j0 = bx * 32 + wave * 4;
        unsigned w2[4][4][8];     // f16-pair weights of Whh0
        float    wx[4][4];        // fp32 x-weights (lane < 33)
        float    bs[4][4];
#pragma unroll
        for (int jj = 0; jj < 4; ++jj) {
#pragma unroll
            for (int g = 0; g < 4; ++g) {
                const int row = g * Hn + (j0 + jj);
                const float* wr = Whh0 + (size_t)row * Hn;
#pragma unroll
                for (int k = 0; k < 8; ++k) {
                    int c = lane + 64 * k;
                    w2[jj][g][k] = pack2(wr[2 * c], wr[2 * c + 1]);
                }
                wx[jj][g] = (lane < INW) ? Wih0[row * INW + lane] : 0.0f;
                bs[jj][g] = bih0[row] + bhh0[row];
            }
        }
        float cst[4], hcur[4];
#pragma unroll
        for (int jj = 0; jj < 4; ++jj) { cst[jj] = cel0[j0 + jj]; hcur[jj] = 0.0f; }

        for (int s = 0; s < Bn; ++s) {
            const int b = s & 1;
            float xv = xin[s * INW + (lane < INW ? lane : 0)];  // prefetch (L2-hot)
            if (s == 0) {
                int q = wave * 64 + lane;
                hs2[0][q] = pack2(hid0[2 * q], hid0[2 * q + 1]);
            } else {
                // detect: one coalesced flag load per wave per round
                poll_flag32(flags + (size_t)(s - 1) * FLAGSTRIDE, 32u);
                // data: one dword per lane, whole h0 half in one round
                unsigned d = load4_coherent(hx + (size_t)(s - 1) * ROWU + wave * 64 + lane);
                hs2[b][wave * 64 + lane] = d;
            }
            __syncthreads();                   // barrier A: hs2[b] ready

            float acc[4][4];
#pragma unroll
            for (int jj = 0; jj < 4; ++jj)
#pragma unroll
                for (int g = 0; g < 4; ++g) acc[jj][g] = wx[jj][g] * xv;
#pragma unroll
            for (int k = 0; k < 8; ++k) {
                unsigned hv = hs2[b][lane + 64 * k];   // 2-way bank alias: free
#pragma unroll
                for (int jj = 0; jj < 4; ++jj)
#pragma unroll
                    for (int g = 0; g < 4; ++g)
                        acc[jj][g] = dot2acc(w2[jj][g][k], hv, acc[jj][g]);
            }

#pragma unroll
            for (int off = 32; off >= 1; off >>= 1)
#pragma unroll
                for (int jj = 0; jj < 4; ++jj)
#pragma unroll
                    for (int g = 0; g < 4; ++g)
                        acc[jj][g] += __shfl_xor(acc[jj][g], off);

#pragma unroll
            for (int jj = 0; jj < 4; ++jj) {
                float gi = sigmoidf_(acc[jj][0] + bs[jj][0]);
                float gf = sigmoidf_(acc[jj][1] + bs[jj][1]);
                float gg = tanhf_   (acc[jj][2] + bs[jj][2]);
                float go = sigmoidf_(acc[jj][3] + bs[jj][3]);
                cst[jj] = gf * cst[jj] + gi * gg;
                hcur[jj] = go * tanhf_(cst[jj]);
            }
            // stage 2 u32 per wave; wave 0 bursts the block's 64 B segment,
            // then (ordered by vmcnt 0) bumps the row's h0 counter
            if (lane == 0) {
                stg[2 * wave]     = pack2(hcur[0], hcur[1]);
                stg[2 * wave + 1] = pack2(hcur[2], hcur[3]);
            }
            __syncthreads();                   // barrier B: stg ready; hs2 reads done
            if (wave == 0) {
                if (lane < 4) {
                    uint4v v = *(const uint4v*)&stg[4 * lane];
                    char* dst = (char*)(hx + (size_t)s * ROWU) + bx * 64 + lane * 16;
                    store16_coherent(dst, v);
                }
                wait_stores();
                if (lane == 0)
                    atomicAdd(flags + (size_t)s * FLAGSTRIDE, 1u);
            }
        }
        if (lane == 0) {
#pragma unroll
            for (int jj = 0; jj < 4; ++jj) {
                out[OUTS + j0 + jj] = hcur[jj];            // hf layer 0
                out[OUTS + 2 * Hn + j0 + jj] = cst[jj];    // cf layer 0
            }
        }
    } else {
        // ========== layer 1 : 64 blocks, wave owns 2 h-indices ==========
        const int blk = bx - 32;
        const int j0  = blk * 16 + wave * 2;
        unsigned w2[2][4][16];    // k<8: Wih1 (vs h0[t]) ; k>=8: Whh1 (vs h1[t-1])
        float    bs[2][4];
#pragma unroll
        for (int jj = 0; jj < 2; ++jj) {
#pragma unroll
            for (int g = 0; g < 4; ++g) {
                const int row = g * Hn + (j0 + jj);
                const float* wr1 = Wih1 + (size_t)row * Hn;
                const float* wr2 = Whh1 + (size_t)row * Hn;
#pragma unroll
                for (int k = 0; k < 8; ++k) {
                    int c = lane + 64 * k;
                    w2[jj][g][k]     = pack2(wr1[2 * c], wr1[2 * c + 1]);
                    w2[jj][g][8 + k] = pack2(wr2[2 * c], wr2[2 * c + 1]);
                }
                bs[jj][g] = bih1[row] + bhh1[row];
            }
        }
        float cst[2], hcur[2];
#pragma unroll
        for (int jj = 0; jj < 2; ++jj) { cst[jj] = cel0[Hn + j0 + jj]; hcur[jj] = 0.0f; }

        // publish initial h1 into row 0's h1 half, then bump h1cnt[0]
        if (wave == 0) {
            if (lane < 2) {
                int base = Hn + blk * 16 + lane * 8;
                uint4v v;
                v.x = pack2(hid0[base],     hid0[base + 1]);
                v.y = pack2(hid0[base + 2], hid0[base + 3]);
                v.z = pack2(hid0[base + 4], hid0[base + 5]);
                v.w = pack2(hid0[base + 6], hid0[base + 7]);
                char* dst = (char*)(hx) + 2048 + blk * 32 + lane * 16;
                store16_coherent(dst, v);
            }
            wait_stores();
            if (lane == 0)
                atomicAdd(flags + 1, 1u);      // flag[0].h1cnt
        }

        const unsigned long long target = 32ull | (64ull << 32);  // h0==32, h1==64
        for (int s = 1; s <= Bn; ++s) {
            const int t = s - 1;               // LSTM step this superstep computes
            const int b = s & 1;
            // detect both halves in one dwordx2 flag poll (coalesced per wave)
            poll_flag64((const unsigned long long*)(flags + (size_t)(s - 1) * FLAGSTRIDE),
                        target);
            // data: one dwordx2 per lane covers the whole 4 KB row
            unsigned long long d = load8_coherent(
                (const unsigned long long*)(hx + (size_t)(s - 1) * ROWU) + wave * 64 + lane);
            int q = 2 * (wave * 64 + lane);
            hs2[b][q]     = (unsigned)d;
            hs2[b][q + 1] = (unsigned)(d >> 32);
            __syncthreads();                   // barrier A: hs2[b] ready

            float acc[2][4];
#pragma unroll
            for (int jj = 0; jj < 2; ++jj)
#pragma unroll
                for (int g = 0; g < 4; ++g) acc[jj][g] = 0.0f;
#pragma unroll
            for (int k = 0; k < 16; ++k) {
                unsigned hv = hs2[b][lane + 64 * k];
#pragma unroll
                for (int jj = 0; jj < 2; ++jj)
#pragma unroll
                    for (int g = 0; g < 4; ++g)
                        acc[jj][g] = dot2acc(w2[jj][g][k], hv, acc[jj][g]);
            }

#pragma unroll
            for (int off = 32; off >= 1; off >>= 1)
#pragma unroll
                for (int jj = 0; jj < 2; ++jj)
#pragma unroll
                    for (int g = 0; g < 4; ++g)
                        acc[jj][g] += __shfl_xor(acc[jj][g], off);

#pragma unroll
            for (int jj = 0; jj < 2; ++jj) {
                float gi = sigmoidf_(acc[jj][0] + bs[jj][0]);
                float gf = sigmoidf_(acc[jj][1] + bs[jj][1]);
                float gg = tanhf_   (acc[jj][2] + bs[jj][2]);
                float go = sigmoidf_(acc[jj][3] + bs[jj][3]);
                cst[jj] = gf * cst[jj] + gi * gg;
                hcur[jj] = go * tanhf_(cst[jj]);
            }
            if (lane == 0) {
                stg[wave] = pack2(hcur[0], hcur[1]);
                float2 o2 = make_float2(fmaxf(hcur[0], 0.0f), fmaxf(hcur[1], 0.0f));
                *(float2*)(out + (size_t)t * Hn + j0) = o2;   // outputs[t] = relu(h1)
            }
            __syncthreads();                   // barrier B: stg ready; hs2 reads done
            if (wave == 0) {
                if (lane < 2) {
                    uint4v v = *(const uint4v*)&stg[4 * lane];
                    char* dst = (char*)(hx + (size_t)s * ROWU) + 2048 + blk * 32 + lane * 16;
                    store16_coherent(dst, v);  // h1[t] into row s's h1 half
                }
                wait_stores();
                if (lane == 0)
                    atomicAdd(flags + (size_t)s * FLAGSTRIDE + 1, 1u);
            }
        }
        if (lane == 0) {
#pragma unroll
            for (int jj = 0; jj < 2; ++jj) {
                out[OUTS + Hn + j0 + jj] = hcur[jj];           // hf layer 1
                out[OUTS + 3 * Hn + j0 + jj] = cst[jj];        // cf layer 1
            }
        }
    }
}

extern "C" void kernel_launch(void* const* d_in, const int* in_sizes, int n_in,
                              void* d_out, int out_size, void* d_ws, size_t ws_size,
                              hipStream_t stream) {
    const float* x        = (const float*)d_in[0];
    const int*   ip       = (const int*)d_in[1];
    const int*   port     = (const int*)d_in[2];
    const float* hidden   = (const float*)d_in[3];
    const float* cell     = (const float*)d_in[4];
    const float* ip_emb   = (const float*)d_in[5];
    const float* port_emb = (const float*)d_in[6];
    const float* Wih0     = (const float*)d_in[7];
    const float* Whh0     = (const float*)d_in[8];
    const float* bih0     = (const float*)d_in[9];
    const float* bhh0     = (const float*)d_in[10];
    const float* Wih1     = (const float*)d_in[11];
    const float* Whh1     = (const float*)d_in[12];
    const float* bih1     = (const float*)d_in[13];
    const float* bhh1     = (const float*)d_in[14];
    float* out = (float*)d_out;

    // ws layout: hx ((Bn+1) x 1024 u32 = 16.8 MB, flag-gated so no init)
    //          | flags ((Bn+1) x 16 u32 = 256 KB, memset-zeroed each launch)
    //          | xin (4096 x 33 f32).
    unsigned* hx    = (unsigned*)d_ws;
    unsigned* flags = hx + (size_t)(Bn + 1) * ROWU;
    float*    xin   = (float*)(flags + (size_t)(Bn + 1) * FLAGSTRIDE);

    hipMemsetAsync(flags, 0, (size_t)(Bn + 1) * FLAGSTRIDE * sizeof(unsigned), stream);

    prep_kernel<<<dim3((Bn * INW + 255) / 256), dim3(256), 0, stream>>>(
        x, ip, port, ip_emb, port_emb, xin);

    lstm_kernel<<<dim3(96), dim3(TPB), 0, stream>>>(
        xin, hidden, cell, Wih0, Whh0, bih0, bhh0, Wih1, Whh1, bih1, bhh1,
        out, hx, flags);
}

// Round 7
// 21104.578 us; speedup vs baseline: 25.5438x; 1.5322x over previous
//
#include <hip/hip_runtime.h>
#include <hip/hip_fp16.h>
#include <math.h>

#define Hn 1024
#define Bn 4096
#define INW 33
#define OUTS (Bn * Hn)
#define TPB 512
#define ROW64 1024     // u64 packets/row: [h0: 512 | h1: 512]; packet = {u32 payload(2xf16), u32 tag}
#define RSLOTS 8       // ring depth; L0 lead over L1 bounded by the s-7 gate
#define BAILOUT (1 << 22)   // ~1 s worst; then accept-anything -> fast passed:false, not a wedge

typedef _Float16 half2v __attribute__((ext_vector_type(2)));
typedef unsigned uint4v __attribute__((ext_vector_type(4)));

// ============ calibrated latency model (R9 vs R14 measurement) ============
// One device-coherent leg (sc0sc1 store -> LLC-visible -> observed by poll)
// costs ~1.3-1.6 us. R9 (detect==data, 2.5 legs): 4.15 us/step. R14 (flag
// scheme, +store-ack +atomic +post-detect data load = 4.5 legs): 7.9 us/step,
// DESPITE cutting FETCH 305->114 MB. Lesson: the exchange is LEG-LATENCY
// bound, not traffic bound. Never separate detection from data; publish at
// the earliest instant; keep poll rounds short.

__device__ __forceinline__ float sigmoidf_(float x) {
    return 1.0f / (1.0f + __expf(-x));
}
__device__ __forceinline__ float tanhf_(float x) {
    float e = __expf(-2.0f * fabsf(x));
    float r = (1.0f - e) / (1.0f + e);
    return copysignf(r, x);
}
__device__ __forceinline__ unsigned pack2(float a, float b) {
    __half2 h = __floats2half2_rn(a, b);
    return __builtin_bit_cast(unsigned, h);
}
__device__ __forceinline__ float dot2acc(unsigned w, unsigned hv, float acc) {
#if __has_builtin(__builtin_amdgcn_fdot2)
    return __builtin_amdgcn_fdot2(__builtin_bit_cast(half2v, w),
                                  __builtin_bit_cast(half2v, hv), acc, false);
#else
    __half2 wh = __builtin_bit_cast(__half2, w);
    __half2 hh = __builtin_bit_cast(__half2, hv);
    float2 wf = __half22float2(wh), hf = __half22float2(hh);
    return acc + wf.x * hf.x + wf.y * hf.y;
#endif
}

__device__ __forceinline__ void store16_coherent(void* dst, uint4v v) {
    asm volatile("global_store_dwordx4 %0, %1, off sc0 sc1"
                 :: "v"(dst), "v"(v) : "memory");
}
__device__ __forceinline__ void store8_coherent(void* dst, unsigned long long v) {
    asm volatile("global_store_dwordx2 %0, %1, off sc0 sc1"
                 :: "v"(dst), "v"(v) : "memory");
}

// Wave-wide half-row spin: ONE wave covers 512 packets (lane L owns packets
// [8L, 8L+8), 4x dwordx4 in flight). Detection and data are the SAME loads
// (leg-minimal). Fewer outstanding requests than per-lane polling (64x5 vs
// 512x1 per block-round) -> shorter queue-dominated rounds.
__device__ __forceinline__ void spin_half(const unsigned long long* hb, int lane,
                                          unsigned tag, unsigned* dst) {
    const unsigned long long* p = hb + 8 * lane;
    uint4v q0, q1, q2, q3;
    int rounds = 0;
    for (;;) {
        asm volatile(
            "global_load_dwordx4 %0, %4, off sc0 sc1\n\t"
            "global_load_dwordx4 %1, %4, off offset:16 sc0 sc1\n\t"
            "global_load_dwordx4 %2, %4, off offset:32 sc0 sc1\n\t"
            "global_load_dwordx4 %3, %4, off offset:48 sc0 sc1\n\t"
            "s_waitcnt vmcnt(0)"
            : "=v"(q0), "=v"(q1), "=v"(q2), "=v"(q3)
            : "v"(p) : "memory");
        bool ok = (q0.y == tag) & (q0.w == tag) & (q1.y == tag) & (q1.w == tag)
                & (q2.y == tag) & (q2.w == tag) & (q3.y == tag) & (q3.w == tag);
        if (__all(ok)) break;
        if (++rounds > BAILOUT) break;   // accept-anything: fail fast, don't wedge
    }
    dst[8 * lane + 0] = q0.x;  dst[8 * lane + 1] = q0.z;
    dst[8 * lane + 2] = q1.x;  dst[8 * lane + 3] = q1.z;
    dst[8 * lane + 4] = q2.x;  dst[8 * lane + 5] = q2.z;
    dst[8 * lane + 6] = q3.x;  dst[8 * lane + 7] = q3.z;
}

// L0 variant: also gates on the ring-reuse condition. Publishing row s
// overwrites victim row s-8's h0 half; safe iff all 64 L1 blocks finished
// consuming row s-8, which is proven by row s-7's h1-half being complete
// (L1 publishes h1 into row u only after consuming row u-1). Lane L checks
// L1 block L's h1 packet of the gate row; folded into the same poll round
// (zero extra legs; normally already satisfied -> free).
__device__ __forceinline__ void spin_l0_row(const unsigned long long* rb,
                                            const unsigned long long* gb,
                                            int lane, unsigned tag,
                                            unsigned gtag, int use_gate,
                                            unsigned* dst) {
    const unsigned long long* p  = rb + 8 * lane;
    const unsigned long long* gp = gb + 512 + 8 * lane;   // L1 block `lane`'s packet
    uint4v q0, q1, q2, q3;
    unsigned long long g;
    int rounds = 0;
    for (;;) {
        asm volatile(
            "global_load_dwordx4 %0, %5, off sc0 sc1\n\t"
            "global_load_dwordx4 %1, %5, off offset:16 sc0 sc1\n\t"
            "global_load_dwordx4 %2, %5, off offset:32 sc0 sc1\n\t"
            "global_load_dwordx4 %3, %5, off offset:48 sc0 sc1\n\t"
            "global_load_dwordx2 %4, %6, off sc0 sc1\n\t"
            "s_waitcnt vmcnt(0)"
            : "=v"(q0), "=v"(q1), "=v"(q2), "=v"(q3), "=v"(g)
            : "v"(p), "v"(gp) : "memory");
        bool ok = (q0.y == tag) & (q0.w == tag) & (q1.y == tag) & (q1.w == tag)
                & (q2.y == tag) & (q2.w == tag) & (q3.y == tag) & (q3.w == tag);
        if (use_gate) ok &= ((unsigned)(g >> 32) == gtag);
        if (__all(ok)) break;
        if (++rounds > BAILOUT) break;
    }
    dst[8 * lane + 0] = q0.x;  dst[8 * lane + 1] = q0.z;
    dst[8 * lane + 2] = q1.x;  dst[8 * lane + 3] = q1.z;
    dst[8 * lane + 4] = q2.x;  dst[8 * lane + 5] = q2.z;
    dst[8 * lane + 6] = q3.x;  dst[8 * lane + 7] = q3.z;
}

// xin = [x | ip_emb[ip] | port_emb[port]]  (4096 x 33)
__global__ void prep_kernel(const float* __restrict__ x, const int* __restrict__ ip,
                            const int* __restrict__ port, const float* __restrict__ ip_emb,
                            const float* __restrict__ port_emb, float* __restrict__ xin) {
    int gid = blockIdx.x * blockDim.x + threadIdx.x;
    if (gid < Bn * INW) {
        int t = gid / INW;
        int k = gid - t * INW;
        float v;
        if (k < 17) {
            v = x[t * 17 + k];
        } else if (k < 25) {
            v = ip_emb[ip[t * 8 + (k - 17)]];
        } else {
            int kk = k - 25;
            v = port_emb[port[t * 2 + (kk >> 2)] * 4 + (kk & 3)];
        }
        xin[gid] = v;
    }
}

// Skewed supersteps (R7): row s = [h0[s] | h1[s-1]], packets tagged s+1.
// R15 structure: 8-slot ring (64 KB, LLC-hot) of tagged rows; per-wave
// IMMEDIATE publish (no barrier B / staging — per-packet tags make shared-
// line partial stores harmless; earliest possible visibility); wave-wide
// dwordx4 polling (wave 0 covers h0-half, wave 1 h1-half), detect==data.
// hs2 double-buffer reuse is ordered by barrier A alone (validated R10/R15
// reasoning: a wave writes hs2[b] for step s+2 only after barrier A of s+1,
// which all waves reach only after their step-s reads of hs2[b]).
// Prior lessons: R8 (1024-thr VGPR cliff), R10 (untagged scatter = tear),
// R12/R13 (co-residency/VGPR contracts), R14 (leg model, header comment).
__global__ void __launch_bounds__(TPB, 2) lstm_kernel(
    const float* __restrict__ xin,
    const float* __restrict__ hid0, const float* __restrict__ cel0,
    const float* __restrict__ Wih0, const float* __restrict__ Whh0,
    const float* __restrict__ bih0, const float* __restrict__ bhh0,
    const float* __restrict__ Wih1, const float* __restrict__ Whh1,
    const float* __restrict__ bih1, const float* __restrict__ bhh1,
    float* __restrict__ out,
    unsigned long long* __restrict__ ring)   // [RSLOTS][ROW64]
{
    __shared__ unsigned hs2[2][1024];          // double-buffered half2 h chunks
    const int tid  = threadIdx.x;
    const int lane = tid & 63;
    const int wave = tid >> 6;                 // 0..7
    const int bx   = blockIdx.x;

    if (bx < 32) {
        // ========== layer 0 : 32 blocks, wave owns 4 h-indices ==========
        const int j0 = bx * 32 + wave * 4;
        unsigned w2[4][4][8];     // f16-pair weights of Whh0
        float    wx[4][4];        // fp32 x-weights (lane < 33)
        float    bs[4][4];
#pragma unroll
        for (int jj = 0; jj < 4; ++jj) {
#pragma unroll
            for (int g = 0; g < 4; ++g) {
                const int row = g * Hn + (j0 + jj);
                const float* wr = Whh0 + (size_t)row * Hn;
#pragma unroll
                for (int k = 0; k < 8; ++k) {
                    int c = lane + 64 * k;
                    w2[jj][g][k] = pack2(wr[2 * c], wr[2 * c + 1]);
                }
                wx[jj][g] = (lane < INW) ? Wih0[row * INW + lane] : 0.0f;
                bs[jj][g] = bih0[row] + bhh0[row];
            }
        }
        float cst[4], hcur[4];
#pragma unroll
        for (int jj = 0; jj < 4; ++jj) { cst[jj] = cel0[j0 + jj]; hcur[jj] = 0.0f; }

        for (int s = 0; s < Bn; ++s) {
            const int b = s & 1;
            float xv = xin[s * INW + (lane < INW ? lane : 0)];  // prefetch (L2-hot)
            if (wave == 0) {
                if (s == 0) {
#pragma unroll
                    for (int k = 0; k < 8; ++k) {
                        int q = k * 64 + lane;
                        hs2[0][q] = pack2(hid0[2 * q], hid0[2 * q + 1]);
                    }
                } else {
                    const unsigned long long* rb =
                        ring + (size_t)((s - 1) & (RSLOTS - 1)) * ROW64;
                    const unsigned long long* gb =
                        ring + (size_t)((s - 7) & (RSLOTS - 1)) * ROW64;
                    spin_l0_row(rb, gb, lane, (unsigned)s,
                                (unsigned)(s - 6), s >= 8, &hs2[b][0]);
                }
            }
            __syncthreads();                   // barrier A: hs2[b] ready

            float acc[4][4];
#pragma unroll
            for (int jj = 0; jj < 4; ++jj)
#pragma unroll
                for (int g = 0; g < 4; ++g) acc[jj][g] = wx[jj][g] * xv;
#pragma unroll
            for (int k = 0; k < 8; ++k) {
                unsigned hv = hs2[b][lane + 64 * k];   // 2-way bank alias: free
#pragma unroll
                for (int jj = 0; jj < 4; ++jj)
#pragma unroll
                    for (int g = 0; g < 4; ++g)
                        acc[jj][g] = dot2acc(w2[jj][g][k], hv, acc[jj][g]);
            }

#pragma unroll
            for (int off = 32; off >= 1; off >>= 1)
#pragma unroll
                for (int jj = 0; jj < 4; ++jj)
#pragma unroll
                    for (int g = 0; g < 4; ++g)
                        acc[jj][g] += __shfl_xor(acc[jj][g], off);

#pragma unroll
            for (int jj = 0; jj < 4; ++jj) {
                float gi = sigmoidf_(acc[jj][0] + bs[jj][0]);
                float gf = sigmoidf_(acc[jj][1] + bs[jj][1]);
                float gg = tanhf_   (acc[jj][2] + bs[jj][2]);
                float go = sigmoidf_(acc[jj][3] + bs[jj][3]);
                cst[jj] = gf * cst[jj] + gi * gg;
                hcur[jj] = go * tanhf_(cst[jj]);
            }
            // immediate per-wave publish: 2 tagged packets (16 B), earliest
            // possible visibility; no staging, no second barrier
            if (lane == 0) {
                unsigned tg = (unsigned)(s + 1);
                uint4v v;
                v.x = pack2(hcur[0], hcur[1]);  v.y = tg;
                v.z = pack2(hcur[2], hcur[3]);  v.w = tg;
                store16_coherent(
                    (void*)(ring + (size_t)(s & (RSLOTS - 1)) * ROW64 + bx * 16 + wave * 2),
                    v);
            }
        }
        if (lane == 0) {
#pragma unroll
            for (int jj = 0; jj < 4; ++jj) {
                out[OUTS + j0 + jj] = hcur[jj];            // hf layer 0
                out[OUTS + 2 * Hn + j0 + jj] = cst[jj];    // cf layer 0
            }
        }
    } else {
        // ========== layer 1 : 64 blocks, wave owns 2 h-indices ==========
        const int blk = bx - 32;
        const int j0  = blk * 16 + wave * 2;
        unsigned w2[2][4][16];    // k<8: Wih1 (vs h0[t]) ; k>=8: Whh1 (vs h1[t-1])
        float    bs[2][4];
#pragma unroll
        for (int jj = 0; jj < 2; ++jj) {
#pragma unroll
            for (int g = 0; g < 4; ++g) {
                const int row = g * Hn + (j0 + jj);
                const float* wr1 = Wih1 + (size_t)row * Hn;
                const float* wr2 = Whh1 + (size_t)row * Hn;
#pragma unroll
                for (int k = 0; k < 8; ++k) {
                    int c = lane + 64 * k;
                    w2[jj][g][k]     = pack2(wr1[2 * c], wr1[2 * c + 1]);
                    w2[jj][g][8 + k] = pack2(wr2[2 * c], wr2[2 * c + 1]);
                }
                bs[jj][g] = bih1[row] + bhh1[row];
            }
        }
        float cst[2], hcur[2];
#pragma unroll
        for (int jj = 0; jj < 2; ++jj) { cst[jj] = cel0[Hn + j0 + jj]; hcur[jj] = 0.0f; }

        // publish initial h1 into ring slot 0's h1 half (tag 1), per wave
        if (lane == 0) {
            int base = Hn + blk * 16 + wave * 2;
            unsigned long long pkt =
                (1ull << 32) | pack2(hid0[base], hid0[base + 1]);
            store8_coherent((void*)(ring + 512 + blk * 8 + wave), pkt);
        }

        for (int s = 1; s <= Bn; ++s) {
            const int t = s - 1;               // LSTM step this superstep computes
            const int b = s & 1;
            const unsigned long long* rb =
                ring + (size_t)((s - 1) & (RSLOTS - 1)) * ROW64;
            if (wave == 0)
                spin_half(rb,       lane, (unsigned)s, &hs2[b][0]);     // h0[t]
            else if (wave == 1)
                spin_half(rb + 512, lane, (unsigned)s, &hs2[b][512]);   // h1[t-1]
            __syncthreads();                   // barrier A: hs2[b] ready

            float acc[2][4];
#pragma unroll
            for (int jj = 0; jj < 2; ++jj)
#pragma unroll
                for (int g = 0; g < 4; ++g) acc[jj][g] = 0.0f;
#pragma unroll
            for (int k = 0; k < 16; ++k) {
                unsigned hv = hs2[b][lane + 64 * k];
#pragma unroll
                for (int jj = 0; jj < 2; ++jj)
#pragma unroll
                    for (int g = 0; g < 4; ++g)
                        acc[jj][g] = dot2acc(w2[jj][g][k], hv, acc[jj][g]);
            }

#pragma unroll
            for (int off = 32; off >= 1; off >>= 1)
#pragma unroll
                for (int jj = 0; jj < 2; ++jj)
#pragma unroll
                    for (int g = 0; g < 4; ++g)
                        acc[jj][g] += __shfl_xor(acc[jj][g], off);

#pragma unroll
            for (int jj = 0; jj < 2; ++jj) {
                float gi = sigmoidf_(acc[jj][0] + bs[jj][0]);
                float gf = sigmoidf_(acc[jj][1] + bs[jj][1]);
                float gg = tanhf_   (acc[jj][2] + bs[jj][2]);
                float go = sigmoidf_(acc[jj][3] + bs[jj][3]);
                cst[jj] = gf * cst[jj] + gi * gg;
                hcur[jj] = go * tanhf_(cst[jj]);
            }
            // immediate per-wave publish: 1 tagged packet (8 B) + relu output
            if (lane == 0) {
                unsigned long long pkt =
                    (((unsigned long long)(s + 1)) << 32) | pack2(hcur[0], hcur[1]);
                store8_coherent(
                    (void*)(ring + (size_t)(s & (RSLOTS - 1)) * ROW64 + 512 + blk * 8 + wave),
                    pkt);
                float2 o2 = make_float2(fmaxf(hcur[0], 0.0f), fmaxf(hcur[1], 0.0f));
                *(float2*)(out + (size_t)t * Hn + j0) = o2;   // outputs[t] = relu(h1)
            }
        }
        if (lane == 0) {
#pragma unroll
            for (int jj = 0; jj < 2; ++jj) {
                out[OUTS + Hn + j0 + jj] = hcur[jj];           // hf layer 1
                out[OUTS + 3 * Hn + j0 + jj] = cst[jj];        // cf layer 1
            }
        }
    }
}

extern "C" void kernel_launch(void* const* d_in, const int* in_sizes, int n_in,
                              void* d_out, int out_size, void* d_ws, size_t ws_size,
                              hipStream_t stream) {
    const float* x        = (const float*)d_in[0];
    const int*   ip       = (const int*)d_in[1];
    const int*   port     = (const int*)d_in[2];
    const float* hidden   = (const float*)d_in[3];
    const float* cell     = (const float*)d_in[4];
    const float* ip_emb   = (const float*)d_in[5];
    const float* port_emb = (const float*)d_in[6];
    const float* Wih0     = (const float*)d_in[7];
    const float* Whh0     = (const float*)d_in[8];
    const float* bih0     = (const float*)d_in[9];
    const float* bhh0     = (const float*)d_in[10];
    const float* Wih1     = (const float*)d_in[11];
    const float* Whh1     = (const float*)d_in[12];
    const float* bih1     = (const float*)d_in[13];
    const float* bhh1     = (const float*)d_in[14];
    float* out = (float*)d_out;

    // ws layout: ring (8 x 1024 u64 = 64 KB, LLC-hot) | xin (4096x33 f32).
    // Tags are s+1; 0xAA poison never matches; ring slot reuse is guarded by
    // the L0 s-7 gate (see spin_l0_row). No zeroing pass needed.
    unsigned long long* ring = (unsigned long long*)d_ws;
    float* xin = (float*)(ring + (size_t)RSLOTS * ROW64);

    prep_kernel<<<dim3((Bn * INW + 255) / 256), dim3(256), 0, stream>>>(
        x, ip, port, ip_emb, port_emb, xin);

    lstm_kernel<<<dim3(96), dim3(TPB), 0, stream>>>(
        xin, hidden, cell, Wih0, Whh0, bih0, bhh0, Wih1, Whh1, bih1, bhh1,
        out, ring);
}

// Round 8
// 17367.984 us; speedup vs baseline: 31.0394x; 1.2151x over previous
//
#include <hip/hip_runtime.h>
#include <hip/hip_fp16.h>
#include <math.h>

#define Hn 1024
#define Bn 4096
#define INW 33
#define OUTS (Bn * Hn)
#define TPB 512
#define ROWP 1024   // packets per exchange row: [h0 half (512) | h1 half (512)]
#define BAILROT (1 << 20)   // ~0.4 s of rotations, then dead-latch (fast fail)

typedef _Float16 half2v __attribute__((ext_vector_type(2)));
typedef unsigned uint4v __attribute__((ext_vector_type(4)));

// ============ calibrated model (R9/R10/R14/R15 measurements) ============
// Period 4.15 us/step (R9) = 0.6 us compute + ~2 serialized coherence legs
// (~1.3-1.6 us each incl. visibility) + poll-detection quantization + max-
// of-96-blocks jitter. Hard lessons, each measured twice:
//   - publish cohesion is non-negotiable (R10, R15: scatter -> WRITE 123 MB,
//     +2-4 ms). Staged LDS burst + barrier stays.
//   - detection must equal data (R14: flag scheme -> +15 ms).
//   - poll traffic VOLUME is not a lever (R3, R14, R15).
// R16 lever: pipelined polling. VMEM returns decrement vmcnt in ISSUE ORDER
// (m135), so N same-address loads in flight + s_waitcnt vmcnt(N-1) checks
// the oldest; service times are spaced L/N instead of L -> detection
// quantization ~L/6 vs ~L/2. Guide rule #18 hazard (register-only checks
// hoisted past inline-asm waitcnt) is closed by giving each waitcnt a fake
// "+v" dependency on the register it gates. vmcnt(0) drain on exit keeps
// in-flight loads from clobbering reused registers.

__device__ __forceinline__ float sigmoidf_(float x) {
    return 1.0f / (1.0f + __expf(-x));
}
__device__ __forceinline__ float tanhf_(float x) {
    float e = __expf(-2.0f * fabsf(x));
    float r = (1.0f - e) / (1.0f + e);
    return copysignf(r, x);
}
__device__ __forceinline__ unsigned pack2(float a, float b) {
    __half2 h = __floats2half2_rn(a, b);
    return __builtin_bit_cast(unsigned, h);
}
__device__ __forceinline__ float dot2acc(unsigned w, unsigned hv, float acc) {
#if __has_builtin(__builtin_amdgcn_fdot2)
    return __builtin_amdgcn_fdot2(__builtin_bit_cast(half2v, w),
                                  __builtin_bit_cast(half2v, hv), acc, false);
#else
    __half2 wh = __builtin_bit_cast(__half2, w);
    __half2 hh = __builtin_bit_cast(__half2, hv);
    float2 wf = __half22float2(wh), hf = __half22float2(hh);
    return acc + wf.x * hf.x + wf.y * hf.y;
#endif
}

// L0 slice spin, 3-deep pipelined. Lane i polls packet slice[i]; detection
// and data capture are the SAME load. dead: accept-anything fast path after
// a bailout so a broken protocol fails fast instead of wedging the GPU.
__device__ __forceinline__ unsigned spin_slice(const unsigned long long* slice,
                                               int lane, unsigned tag, int& dead) {
    const unsigned long long* p = slice + lane;
    unsigned long long v0, v1, v2;
    unsigned r;
    if (dead) {
        asm volatile("s_waitcnt vmcnt(0)\n\t"
                     "global_load_dwordx2 %0, %1, off sc0 sc1\n\t"
                     "s_waitcnt vmcnt(0)"
                     : "=v"(v0) : "v"(p) : "memory");
        return (unsigned)v0;
    }
    asm volatile("s_waitcnt vmcnt(0)\n\t"
                 "global_load_dwordx2 %0, %3, off sc0 sc1\n\t"
                 "global_load_dwordx2 %1, %3, off sc0 sc1\n\t"
                 "global_load_dwordx2 %2, %3, off sc0 sc1"
                 : "=v"(v0), "=v"(v1), "=v"(v2) : "v"(p) : "memory");
    int rot = 0;
    for (;;) {
        asm volatile("s_waitcnt vmcnt(2)" : "+v"(v0) :: "memory");
        if (__all((unsigned)(v0 >> 32) == tag)) { r = (unsigned)v0; break; }
        asm volatile("global_load_dwordx2 %0, %1, off sc0 sc1"
                     : "=v"(v0) : "v"(p) : "memory");
        asm volatile("s_waitcnt vmcnt(2)" : "+v"(v1) :: "memory");
        if (__all((unsigned)(v1 >> 32) == tag)) { r = (unsigned)v1; break; }
        asm volatile("global_load_dwordx2 %0, %1, off sc0 sc1"
                     : "=v"(v1) : "v"(p) : "memory");
        asm volatile("s_waitcnt vmcnt(2)" : "+v"(v2) :: "memory");
        if (__all((unsigned)(v2 >> 32) == tag)) { r = (unsigned)v2; break; }
        asm volatile("global_load_dwordx2 %0, %1, off sc0 sc1"
                     : "=v"(v2) : "v"(p) : "memory");
        if (++rot > BAILROT) { dead = 1; r = (unsigned)v2; break; }
    }
    asm volatile("s_waitcnt vmcnt(0)" ::: "memory");   // drain before reg reuse
    return r;
}

// L1 dual-slice spin, 3-deep pipelined pairs (6 loads in flight; vmcnt(4)
// completes the oldest pair). Single exit when both slices current.
__device__ __forceinline__ void spin_slice2(const unsigned long long* sliceA,
                                            const unsigned long long* sliceB,
                                            int lane, unsigned tag,
                                            unsigned& dA, unsigned& dB, int& dead) {
    const unsigned long long* pa = sliceA + lane;
    const unsigned long long* pb = sliceB + lane;
    unsigned long long a0, b0, a1, b1, a2, b2;
    if (dead) {
        asm volatile("s_waitcnt vmcnt(0)\n\t"
                     "global_load_dwordx2 %0, %2, off sc0 sc1\n\t"
                     "global_load_dwordx2 %1, %3, off sc0 sc1\n\t"
                     "s_waitcnt vmcnt(0)"
                     : "=v"(a0), "=v"(b0) : "v"(pa), "v"(pb) : "memory");
        dA = (unsigned)a0; dB = (unsigned)b0;
        return;
    }
    asm volatile("s_waitcnt vmcnt(0)\n\t"
                 "global_load_dwordx2 %0, %6, off sc0 sc1\n\t"
                 "global_load_dwordx2 %1, %7, off sc0 sc1\n\t"
                 "global_load_dwordx2 %2, %6, off sc0 sc1\n\t"
                 "global_load_dwordx2 %3, %7, off sc0 sc1\n\t"
                 "global_load_dwordx2 %4, %6, off sc0 sc1\n\t"
                 "global_load_dwordx2 %5, %7, off sc0 sc1"
                 : "=v"(a0), "=v"(b0), "=v"(a1), "=v"(b1), "=v"(a2), "=v"(b2)
                 : "v"(pa), "v"(pb) : "memory");
    int rot = 0;
    for (;;) {
        asm volatile("s_waitcnt vmcnt(4)" : "+v"(a0), "+v"(b0) :: "memory");
        if (__all(((unsigned)(a0 >> 32) == tag) & ((unsigned)(b0 >> 32) == tag))) {
            dA = (unsigned)a0; dB = (unsigned)b0; break;
        }
        asm volatile("global_load_dwordx2 %0, %2, off sc0 sc1\n\t"
                     "global_load_dwordx2 %1, %3, off sc0 sc1"
                     : "=v"(a0), "=v"(b0) : "v"(pa), "v"(pb) : "memory");
        asm volatile("s_waitcnt vmcnt(4)" : "+v"(a1), "+v"(b1) :: "memory");
        if (__all(((unsigned)(a1 >> 32) == tag) & ((unsigned)(b1 >> 32) == tag))) {
            dA = (unsigned)a1; dB = (unsigned)b1; break;
        }
        asm volatile("global_load_dwordx2 %0, %2, off sc0 sc1\n\t"
                     "global_load_dwordx2 %1, %3, off sc0 sc1"
                     : "=v"(a1), "=v"(b1) : "v"(pa), "v"(pb) : "memory");
        asm volatile("s_waitcnt vmcnt(4)" : "+v"(a2), "+v"(b2) :: "memory");
        if (__all(((unsigned)(a2 >> 32) == tag) & ((unsigned)(b2 >> 32) == tag))) {
            dA = (unsigned)a2; dB = (unsigned)b2; break;
        }
        asm volatile("global_load_dwordx2 %0, %2, off sc0 sc1\n\t"
                     "global_load_dwordx2 %1, %3, off sc0 sc1"
                     : "=v"(a2), "=v"(b2) : "v"(pa), "v"(pb) : "memory");
        if (++rot > BAILROT) { dead = 1; dA = (unsigned)a2; dB = (unsigned)b2; break; }
    }
    asm volatile("s_waitcnt vmcnt(0)" ::: "memory");   // drain before reg reuse
}

__device__ __forceinline__ void store16_coherent(void* dst, uint4v v) {
    asm volatile("global_store_dwordx4 %0, %1, off sc0 sc1"
                 :: "v"(dst), "v"(v) : "memory");
}

// xin = [x | ip_emb[ip] | port_emb[port]]  (4096 x 33)
__global__ void prep_kernel(const float* __restrict__ x, const int* __restrict__ ip,
                            const int* __restrict__ port, const float* __restrict__ ip_emb,
                            const float* __restrict__ port_emb, float* __restrict__ xin) {
    int gid = blockIdx.x * blockDim.x + threadIdx.x;
    if (gid < Bn * INW) {
        int t = gid / INW;
        int k = gid - t * INW;
        float v;
        if (k < 17) {
            v = x[t * 17 + k];
        } else if (k < 25) {
            v = ip_emb[ip[t * 8 + (k - 17)]];
        } else {
            int kk = k - 25;
            v = port_emb[port[t * 2 + (kk >> 2)] * 4 + (kk & 3)];
        }
        xin[gid] = v;
    }
}

// Skewed supersteps (R7 protocol): row s holds [h0[s] | h1[s-1]], all packets
// tagged s+1. R9 structure restored EXACTLY (16.98 ms baseline: slice-spin
// detect==data, 2 barriers, staged cohesive publish bursts, double-buffered
// LDS, 512-thr blocks). R16 = R9 + 3-deep pipelined spins (header comment).
__global__ void __launch_bounds__(TPB, 2) lstm_kernel(
    const float* __restrict__ xin,
    const float* __restrict__ hid0, const float* __restrict__ cel0,
    const float* __restrict__ Wih0, const float* __restrict__ Whh0,
    const float* __restrict__ bih0, const float* __restrict__ bhh0,
    const float* __restrict__ Wih1, const float* __restrict__ Whh1,
    const float* __restrict__ bih1, const float* __restrict__ bhh1,
    float* __restrict__ out,
    unsigned long long* __restrict__ rowpkt)  // [Bn+1][ROWP]
{
    __shared__ unsigned hs2[2][1024];          // double-buffered half2 h chunks
    __shared__ unsigned long long stg[16];     // outgoing packet staging
    const int tid  = threadIdx.x;
    const int lane = tid & 63;
    const int wave = tid >> 6;                 // 0..7
    const int bx   = blockIdx.x;

    if (bx < 32) {
        // ========== layer 0 : 32 blocks, wave owns 4 h-indices ==========
        const int j0 = bx * 32 + wave * 4;
        unsigned w2[4][4][8];     // f16-pair weights of Whh0
        float    wx[4][4];        // fp32 x-weights (lane < 33)
        float    bs[4][4];
#pragma unroll
        for (int jj = 0; jj < 4; ++jj) {
#pragma unroll
            for (int g = 0; g < 4; ++g) {
                const int row = g * Hn + (j0 + jj);
                const float* wr = Whh0 + (size_t)row * Hn;
#pragma unroll
                for (int k = 0; k < 8; ++k) {
                    int c = lane + 64 * k;
                    w2[jj][g][k] = pack2(wr[2 * c], wr[2 * c + 1]);
                }
                wx[jj][g] = (lane < INW) ? Wih0[row * INW + lane] : 0.0f;
                bs[jj][g] = bih0[row] + bhh0[row];
            }
        }
        float cst[4], hcur[4];
#pragma unroll
        for (int jj = 0; jj < 4; ++jj) { cst[jj] = cel0[j0 + jj]; hcur[jj] = 0.0f; }

        int dead = 0;
        for (int s = 0; s < Bn; ++s) {
            const int b = s & 1;
            float xv = xin[s * INW + (lane < INW ? lane : 0)];  // prefetch (L2-hot)
            // waves 0-7 each spin one 64-packet slice of the h0 half
            if (s == 0) {
                int q = wave * 64 + lane;
                hs2[0][q] = pack2(hid0[2 * q], hid0[2 * q + 1]);
            } else {
                unsigned d = spin_slice(rowpkt + (size_t)(s - 1) * ROWP + wave * 64,
                                        lane, (unsigned)s, dead);
                hs2[b][wave * 64 + lane] = d;
            }
            __syncthreads();                   // barrier A: hs2[b] ready

            float acc[4][4];
#pragma unroll
            for (int jj = 0; jj < 4; ++jj)
#pragma unroll
                for (int g = 0; g < 4; ++g) acc[jj][g] = wx[jj][g] * xv;
#pragma unroll
            for (int k = 0; k < 8; ++k) {
                unsigned hv = hs2[b][lane + 64 * k];   // 2-way bank alias: free
#pragma unroll
                for (int jj = 0; jj < 4; ++jj)
#pragma unroll
                    for (int g = 0; g < 4; ++g)
                        acc[jj][g] = dot2acc(w2[jj][g][k], hv, acc[jj][g]);
            }

#pragma unroll
            for (int off = 32; off >= 1; off >>= 1)
#pragma unroll
                for (int jj = 0; jj < 4; ++jj)
#pragma unroll
                    for (int g = 0; g < 4; ++g)
                        acc[jj][g] += __shfl_xor(acc[jj][g], off);

#pragma unroll
            for (int jj = 0; jj < 4; ++jj) {
                float gi = sigmoidf_(acc[jj][0] + bs[jj][0]);
                float gf = sigmoidf_(acc[jj][1] + bs[jj][1]);
                float gg = tanhf_   (acc[jj][2] + bs[jj][2]);
                float go = sigmoidf_(acc[jj][3] + bs[jj][3]);
                cst[jj] = gf * cst[jj] + gi * gg;
                hcur[jj] = go * tanhf_(cst[jj]);
            }
            // stage 2 packets per wave; wave 0 bursts the block's 128 B segment
            if (lane == 0) {
                unsigned long long tw = ((unsigned long long)(s + 1)) << 32;
                stg[2 * wave]     = tw | pack2(hcur[0], hcur[1]);
                stg[2 * wave + 1] = tw | pack2(hcur[2], hcur[3]);
            }
            __syncthreads();                   // barrier B: stg ready; hs2 reads done
            if (wave == 0 && lane < 8) {
                uint4v v = *(const uint4v*)&stg[2 * lane];
                char* dst = (char*)(rowpkt + (size_t)s * ROWP) + bx * 128 + lane * 16;
                store16_coherent(dst, v);
            }
        }
        if (lane == 0) {
#pragma unroll
            for (int jj = 0; jj < 4; ++jj) {
                out[OUTS + j0 + jj] = hcur[jj];            // hf layer 0
                out[OUTS + 2 * Hn + j0 + jj] = cst[jj];    // cf layer 0
            }
        }
    } else {
        // ========== layer 1 : 64 blocks, wave owns 2 h-indices ==========
        const int blk = bx - 32;
        const int j0  = blk * 16 + wave * 2;
        unsigned w2[2][4][16];    // k<8: Wih1 (vs h0[t]) ; k>=8: Whh1 (vs h1[t-1])
        float    bs[2][4];
#pragma unroll
        for (int jj = 0; jj < 2; ++jj) {
#pragma unroll
            for (int g = 0; g < 4; ++g) {
                const int row = g * Hn + (j0 + jj);
                const float* wr1 = Wih1 + (size_t)row * Hn;
                const float* wr2 = Whh1 + (size_t)row * Hn;
#pragma unroll
                for (int k = 0; k < 8; ++k) {
                    int c = lane + 64 * k;
                    w2[jj][g][k]     = pack2(wr1[2 * c], wr1[2 * c + 1]);
                    w2[jj][g][8 + k] = pack2(wr2[2 * c], wr2[2 * c + 1]);
                }
                bs[jj][g] = bih1[row] + bhh1[row];
            }
        }
        float cst[2], hcur[2];
#pragma unroll
        for (int jj = 0; jj < 2; ++jj) { cst[jj] = cel0[Hn + j0 + jj]; hcur[jj] = 0.0f; }

        // publish initial h1 into row 0's h1 half (tag 1)
        if (wave == 0 && lane < 4) {
            int base = Hn + blk * 16 + 4 * lane;
            uint4v v;
            v.x = pack2(hid0[base],     hid0[base + 1]);  v.y = 1u;
            v.z = pack2(hid0[base + 2], hid0[base + 3]);  v.w = 1u;
            char* dst = (char*)(rowpkt + 512) + blk * 64 + lane * 16;
            store16_coherent(dst, v);
        }

        int dead = 0;
        for (int s = 1; s <= Bn; ++s) {
            const int t = s - 1;               // LSTM step this superstep computes
            const int b = s & 1;
            // 8 waves x 2 slices cover the full 1024-packet row (h0 | h1)
            const unsigned long long* rb = rowpkt + (size_t)(s - 1) * ROWP;
            unsigned dA, dB;
            spin_slice2(rb + wave * 64, rb + 512 + wave * 64, lane, (unsigned)s,
                        dA, dB, dead);
            hs2[b][wave * 64 + lane]       = dA;   // h0[t] chunk
            hs2[b][512 + wave * 64 + lane] = dB;   // h1[t-1] chunk
            __syncthreads();                   // barrier A: hs2[b] ready

            float acc[2][4];
#pragma unroll
            for (int jj = 0; jj < 2; ++jj)
#pragma unroll
                for (int g = 0; g < 4; ++g) acc[jj][g] = 0.0f;
#pragma unroll
            for (int k = 0; k < 16; ++k) {
                unsigned hv = hs2[b][lane + 64 * k];
#pragma unroll
                for (int jj = 0; jj < 2; ++jj)
#pragma unroll
                    for (int g = 0; g < 4; ++g)
                        acc[jj][g] = dot2acc(w2[jj][g][k], hv, acc[jj][g]);
            }

#pragma unroll
            for (int off = 32; off >= 1; off >>= 1)
#pragma unroll
                for (int jj = 0; jj < 2; ++jj)
#pragma unroll
                    for (int g = 0; g < 4; ++g)
                        acc[jj][g] += __shfl_xor(acc[jj][g], off);

#pragma unroll
            for (int jj = 0; jj < 2; ++jj) {
                float gi = sigmoidf_(acc[jj][0] + bs[jj][0]);
                float gf = sigmoidf_(acc[jj][1] + bs[jj][1]);
                float gg = tanhf_   (acc[jj][2] + bs[jj][2]);
                float go = sigmoidf_(acc[jj][3] + bs[jj][3]);
                cst[jj] = gf * cst[jj] + gi * gg;
                hcur[jj] = go * tanhf_(cst[jj]);
            }
            if (lane == 0) {
                unsigned long long tw = ((unsigned long long)(s + 1)) << 32;
                stg[wave] = tw | pack2(hcur[0], hcur[1]);
                float2 o2 = make_float2(fmaxf(hcur[0], 0.0f), fmaxf(hcur[1], 0.0f));
                *(float2*)(out + (size_t)t * Hn + j0) = o2;   // outputs[t] = relu(h1)
            }
            __syncthreads();                   // barrier B: stg ready; hs2 reads done
            if (wave == 0 && lane < 4) {
                uint4v v = *(const uint4v*)&stg[2 * lane];
                char* dst = (char*)(rowpkt + (size_t)s * ROWP + 512) + blk * 64 + lane * 16;
                store16_coherent(dst, v);      // h1[t] into row s's h1 half
            }
        }
        if (lane == 0) {
#pragma unroll
            for (int jj = 0; jj < 2; ++jj) {
                out[OUTS + Hn + j0 + jj] = hcur[jj];           // hf layer 1
                out[OUTS + 3 * Hn + j0 + jj] = cst[jj];        // cf layer 1
            }
        }
    }
}

extern "C" void kernel_launch(void* const* d_in, const int* in_sizes, int n_in,
                              void* d_out, int out_size, void* d_ws, size_t ws_size,
                              hipStream_t stream) {
    const float* x        = (const float*)d_in[0];
    const int*   ip       = (const int*)d_in[1];
    const int*   port     = (const int*)d_in[2];
    const float* hidden   = (const float*)d_in[3];
    const float* cell     = (const float*)d_in[4];
    const float* ip_emb   = (const float*)d_in[5];
    const float* port_emb = (const float*)d_in[6];
    const float* Wih0     = (const float*)d_in[7];
    const float* Whh0     = (const float*)d_in[8];
    const float* bih0     = (const float*)d_in[9];
    const float* bhh0     = (const float*)d_in[10];
    const float* Wih1     = (const float*)d_in[11];
    const float* Whh1     = (const float*)d_in[12];
    const float* bih1     = (const float*)d_in[13];
    const float* bhh1     = (const float*)d_in[14];
    float* out = (float*)d_out;

    // ws layout: rowpkt ((Bn+1) x 1024 u64 = 33.6 MB) | xin (4096x33 f32).
    // Tags are s+1 in the high 32 bits; 0xAA poison never matches -> no
    // zeroing pass needed.
    unsigned long long* rowpkt = (unsigned long long*)d_ws;
    float* xin = (float*)(rowpkt + (size_t)(Bn + 1) * ROWP);

    prep_kernel<<<dim3((Bn * INW + 255) / 256), dim3(256), 0, stream>>>(
        x, ip, port, ip_emb, port_emb, xin);

    lstm_kernel<<<dim3(96), dim3(TPB), 0, stream>>>(
        xin, hidden, cell, Wih0, Whh0, bih0, bhh0, Wih1, Whh1, bih1, bhh1,
        out, rowpkt);
}

// Round 9
// 16998.680 us; speedup vs baseline: 31.7137x; 1.0217x over previous
//
#include <hip/hip_runtime.h>
#include <hip/hip_fp16.h>
#include <math.h>

#define Hn 1024
#define Bn 4096
#define INW 33
#define OUTS (Bn * Hn)
#define TPB 512
#define ROWP 1024   // packets per exchange row: [h0 half (512) | h1 half (512)]
#define BAILROT (1 << 22)   // then accept-anything: fast passed:false, not a wedge

typedef _Float16 half2v __attribute__((ext_vector_type(2)));
typedef unsigned uint4v __attribute__((ext_vector_type(4)));

// ============ calibrated model (R9/R14/R15/R16 measurements) ============
// Period 4.15 us/step (R9) = 0.6 us compute + store-visibility legs +
// poll-round quantization. R16's null (3-deep pipelined polls: pool x3,
// frequency x3, period UNCHANGED) shows the round interval = outstanding
// request pool / LLC service rate -- not issue cadence. Laws (each measured
// at least twice):
//   - publish cohesion is non-negotiable (R10, R15: scatter -> +16-24%).
//   - detection must equal data (R14: flag indirection -> +90%).
//   - traffic bytes are not the lever; REQUEST COUNT plausibly is (R16).
// R17 lever: halve the poll request pool. Each lane polls 2 packets with ONE
// dwordx4 (per-packet tags intact; producer writes are single aligned 16 B
// transactions). L0: 4 polling waves x 64 req = 256/block-round (was 512).
// L1: 8 waves x 64 = 512 (was 1024). Everything else is R9 byte-for-byte.

__device__ __forceinline__ float sigmoidf_(float x) {
    return 1.0f / (1.0f + __expf(-x));
}
__device__ __forceinline__ float tanhf_(float x) {
    float e = __expf(-2.0f * fabsf(x));
    float r = (1.0f - e) / (1.0f + e);
    return copysignf(r, x);
}
__device__ __forceinline__ unsigned pack2(float a, float b) {
    __half2 h = __floats2half2_rn(a, b);
    return __builtin_bit_cast(unsigned, h);
}
__device__ __forceinline__ float dot2acc(unsigned w, unsigned hv, float acc) {
#if __has_builtin(__builtin_amdgcn_fdot2)
    return __builtin_amdgcn_fdot2(__builtin_bit_cast(half2v, w),
                                  __builtin_bit_cast(half2v, hv), acc, false);
#else
    __half2 wh = __builtin_bit_cast(__half2, w);
    __half2 hh = __builtin_bit_cast(__half2, hv);
    float2 wf = __half22float2(wh), hf = __half22float2(hh);
    return acc + wf.x * hf.x + wf.y * hf.y;
#endif
}

// Pair spin: lane L polls packets {2L, 2L+1} of a 128-packet region with one
// dwordx4. Detection and data capture are the SAME load (leg-minimal); each
// 8 B packet self-validates via its own tag, so cross-packet tearing within
// the 16 B read is harmless. One request per lane per round.
__device__ __forceinline__ void spin_pair(const unsigned long long* region,
                                          int lane, unsigned tag,
                                          unsigned& p0, unsigned& p1) {
    const unsigned long long* p = region + 2 * lane;
    uint4v q;
    int rounds = 0;
    for (;;) {
        asm volatile("global_load_dwordx4 %0, %1, off sc0 sc1\n\t"
                     "s_waitcnt vmcnt(0)"
                     : "=v"(q) : "v"(p) : "memory");
        if (__all((q.y == tag) & (q.w == tag))) break;
        if (++rounds > BAILROT) break;   // accept-anything: fail fast, don't wedge
    }
    p0 = q.x;
    p1 = q.z;
}

__device__ __forceinline__ void store16_coherent(void* dst, uint4v v) {
    asm volatile("global_store_dwordx4 %0, %1, off sc0 sc1"
                 :: "v"(dst), "v"(v) : "memory");
}

// xin = [x | ip_emb[ip] | port_emb[port]]  (4096 x 33)
__global__ void prep_kernel(const float* __restrict__ x, const int* __restrict__ ip,
                            const int* __restrict__ port, const float* __restrict__ ip_emb,
                            const float* __restrict__ port_emb, float* __restrict__ xin) {
    int gid = blockIdx.x * blockDim.x + threadIdx.x;
    if (gid < Bn * INW) {
        int t = gid / INW;
        int k = gid - t * INW;
        float v;
        if (k < 17) {
            v = x[t * 17 + k];
        } else if (k < 25) {
            v = ip_emb[ip[t * 8 + (k - 17)]];
        } else {
            int kk = k - 25;
            v = port_emb[port[t * 2 + (kk >> 2)] * 4 + (kk & 3)];
        }
        xin[gid] = v;
    }
}

// Skewed supersteps (R7 protocol): row s holds [h0[s] | h1[s-1]], all packets
// tagged s+1. Superstep s: L0 computes step s from row s-1's h0 half; L1
// computes step s-1 from BOTH halves of row s-1 (single tag phase).
// R9 structure (16.98 ms baseline): slice-spin detect==data, 2 barriers,
// staged cohesive publish bursts, double-buffered LDS, 512-thr blocks.
// R17 = R9 with paired dwordx4 polling (half the request pool; see header).
__global__ void __launch_bounds__(TPB, 2) lstm_kernel(
    const float* __restrict__ xin,
    const float* __restrict__ hid0, const float* __restrict__ cel0,
    const float* __restrict__ Wih0, const float* __restrict__ Whh0,
    const float* __restrict__ bih0, const float* __restrict__ bhh0,
    const float* __restrict__ Wih1, const float* __restrict__ Whh1,
    const float* __restrict__ bih1, const float* __restrict__ bhh1,
    float* __restrict__ out,
    unsigned long long* __restrict__ rowpkt)  // [Bn+1][ROWP]
{
    __shared__ unsigned hs2[2][1024];          // double-buffered half2 h chunks
    __shared__ unsigned long long stg[16];     // outgoing packet staging
    const int tid  = threadIdx.x;
    const int lane = tid & 63;
    const int wave = tid >> 6;                 // 0..7
    const int bx   = blockIdx.x;

    if (bx < 32) {
        // ========== layer 0 : 32 blocks, wave owns 4 h-indices ==========
        const int j0 = bx * 32 + wave * 4;
        unsigned w2[4][4][8];     // f16-pair weights of Whh0
        float    wx[4][4];        // fp32 x-weights (lane < 33)
        float    bs[4][4];
#pragma unroll
        for (int jj = 0; jj < 4; ++jj) {
#pragma unroll
            for (int g = 0; g < 4; ++g) {
                const int row = g * Hn + (j0 + jj);
                const float* wr = Whh0 + (size_t)row * Hn;
#pragma unroll
                for (int k = 0; k < 8; ++k) {
                    int c = lane + 64 * k;
                    w2[jj][g][k] = pack2(wr[2 * c], wr[2 * c + 1]);
                }
                wx[jj][g] = (lane < INW) ? Wih0[row * INW + lane] : 0.0f;
                bs[jj][g] = bih0[row] + bhh0[row];
            }
        }
        float cst[4], hcur[4];
#pragma unroll
        for (int jj = 0; jj < 4; ++jj) { cst[jj] = cel0[j0 + jj]; hcur[jj] = 0.0f; }

        for (int s = 0; s < Bn; ++s) {
            const int b = s & 1;
            float xv = xin[s * INW + (lane < INW ? lane : 0)];  // prefetch (L2-hot)
            // waves 0-3 each poll a 128-packet region of the h0 half (paired
            // dwordx4); waves 4-7 go straight to barrier A (pool halved)
            if (s == 0) {
                int q = wave * 64 + lane;
                hs2[0][q] = pack2(hid0[2 * q], hid0[2 * q + 1]);
            } else if (wave < 4) {
                unsigned p0, p1;
                spin_pair(rowpkt + (size_t)(s - 1) * ROWP + wave * 128,
                          lane, (unsigned)s, p0, p1);
                int q0 = wave * 128 + 2 * lane;
                *(unsigned long long*)&hs2[b][q0] =
                    ((unsigned long long)p1 << 32) | p0;
            }
            __syncthreads();                   // barrier A: hs2[b] ready

            float acc[4][4];
#pragma unroll
            for (int jj = 0; jj < 4; ++jj)
#pragma unroll
                for (int g = 0; g < 4; ++g) acc[jj][g] = wx[jj][g] * xv;
#pragma unroll
            for (int k = 0; k < 8; ++k) {
                unsigned hv = hs2[b][lane + 64 * k];   // 2-way bank alias: free
#pragma unroll
                for (int jj = 0; jj < 4; ++jj)
#pragma unroll
                    for (int g = 0; g < 4; ++g)
                        acc[jj][g] = dot2acc(w2[jj][g][k], hv, acc[jj][g]);
            }

#pragma unroll
            for (int off = 32; off >= 1; off >>= 1)
#pragma unroll
                for (int jj = 0; jj < 4; ++jj)
#pragma unroll
                    for (int g = 0; g < 4; ++g)
                        acc[jj][g] += __shfl_xor(acc[jj][g], off);

#pragma unroll
            for (int jj = 0; jj < 4; ++jj) {
                float gi = sigmoidf_(acc[jj][0] + bs[jj][0]);
                float gf = sigmoidf_(acc[jj][1] + bs[jj][1]);
                float gg = tanhf_   (acc[jj][2] + bs[jj][2]);
                float go = sigmoidf_(acc[jj][3] + bs[jj][3]);
                cst[jj] = gf * cst[jj] + gi * gg;
                hcur[jj] = go * tanhf_(cst[jj]);
            }
            // stage 2 packets per wave; wave 0 bursts the block's 128 B segment
            if (lane == 0) {
                unsigned long long tw = ((unsigned long long)(s + 1)) << 32;
                stg[2 * wave]     = tw | pack2(hcur[0], hcur[1]);
                stg[2 * wave + 1] = tw | pack2(hcur[2], hcur[3]);
            }
            __syncthreads();                   // barrier B: stg ready; hs2 reads done
            if (wave == 0 && lane < 8) {
                uint4v v = *(const uint4v*)&stg[2 * lane];
                char* dst = (char*)(rowpkt + (size_t)s * ROWP) + bx * 128 + lane * 16;
                store16_coherent(dst, v);
            }
        }
        if (lane == 0) {
#pragma unroll
            for (int jj = 0; jj < 4; ++jj) {
                out[OUTS + j0 + jj] = hcur[jj];            // hf layer 0
                out[OUTS + 2 * Hn + j0 + jj] = cst[jj];    // cf layer 0
            }
        }
    } else {
        // ========== layer 1 : 64 blocks, wave owns 2 h-indices ==========
        const int blk = bx - 32;
        const int j0  = blk * 16 + wave * 2;
        unsigned w2[2][4][16];    // k<8: Wih1 (vs h0[t]) ; k>=8: Whh1 (vs h1[t-1])
        float    bs[2][4];
#pragma unroll
        for (int jj = 0; jj < 2; ++jj) {
#pragma unroll
            for (int g = 0; g < 4; ++g) {
                const int row = g * Hn + (j0 + jj);
                const float* wr1 = Wih1 + (size_t)row * Hn;
                const float* wr2 = Whh1 + (size_t)row * Hn;
#pragma unroll
                for (int k = 0; k < 8; ++k) {
                    int c = lane + 64 * k;
                    w2[jj][g][k]     = pack2(wr1[2 * c], wr1[2 * c + 1]);
                    w2[jj][g][8 + k] = pack2(wr2[2 * c], wr2[2 * c + 1]);
                }
                bs[jj][g] = bih1[row] + bhh1[row];
            }
        }
        float cst[2], hcur[2];
#pragma unroll
        for (int jj = 0; jj < 2; ++jj) { cst[jj] = cel0[Hn + j0 + jj]; hcur[jj] = 0.0f; }

        // publish initial h1 into row 0's h1 half (tag 1)
        if (wave == 0 && lane < 4) {
            int base = Hn + blk * 16 + 4 * lane;
            uint4v v;
            v.x = pack2(hid0[base],     hid0[base + 1]);  v.y = 1u;
            v.z = pack2(hid0[base + 2], hid0[base + 3]);  v.w = 1u;
            char* dst = (char*)(rowpkt + 512) + blk * 64 + lane * 16;
            store16_coherent(dst, v);
        }

        for (int s = 1; s <= Bn; ++s) {
            const int t = s - 1;               // LSTM step this superstep computes
            const int b = s & 1;
            // 8 waves x 128 packets cover the full row (h0 | h1) with one
            // paired dwordx4 per lane per round (pool halved vs R9)
            const unsigned long long* rb = rowpkt + (size_t)(s - 1) * ROWP;
            unsigned p0, p1;
            spin_pair(rb + wave * 128, lane, (unsigned)s, p0, p1);
            int q0 = wave * 128 + 2 * lane;
            *(unsigned long long*)&hs2[b][q0] =
                ((unsigned long long)p1 << 32) | p0;
            __syncthreads();                   // barrier A: hs2[b] ready

            float acc[2][4];
#pragma unroll
            for (int jj = 0; jj < 2; ++jj)
#pragma unroll
                for (int g = 0; g < 4; ++g) acc[jj][g] = 0.0f;
#pragma unroll
            for (int k = 0; k < 16; ++k) {
                unsigned hv = hs2[b][lane + 64 * k];
#pragma unroll
                for (int jj = 0; jj < 2; ++jj)
#pragma unroll
                    for (int g = 0; g < 4; ++g)
                        acc[jj][g] = dot2acc(w2[jj][g][k], hv, acc[jj][g]);
            }

#pragma unroll
            for (int off = 32; off >= 1; off >>= 1)
#pragma unroll
                for (int jj = 0; jj < 2; ++jj)
#pragma unroll
                    for (int g = 0; g < 4; ++g)
                        acc[jj][g] += __shfl_xor(acc[jj][g], off);

#pragma unroll
            for (int jj = 0; jj < 2; ++jj) {
                float gi = sigmoidf_(acc[jj][0] + bs[jj][0]);
                float gf = sigmoidf_(acc[jj][1] + bs[jj][1]);
                float gg = tanhf_   (acc[jj][2] + bs[jj][2]);
                float go = sigmoidf_(acc[jj][3] + bs[jj][3]);
                cst[jj] = gf * cst[jj] + gi * gg;
                hcur[jj] = go * tanhf_(cst[jj]);
            }
            if (lane == 0) {
                unsigned long long tw = ((unsigned long long)(s + 1)) << 32;
                stg[wave] = tw | pack2(hcur[0], hcur[1]);
                float2 o2 = make_float2(fmaxf(hcur[0], 0.0f), fmaxf(hcur[1], 0.0f));
                *(float2*)(out + (size_t)t * Hn + j0) = o2;   // outputs[t] = relu(h1)
            }
            __syncthreads();                   // barrier B: stg ready; hs2 reads done
            if (wave == 0 && lane < 4) {
                uint4v v = *(const uint4v*)&stg[2 * lane];
                char* dst = (char*)(rowpkt + (size_t)s * ROWP + 512) + blk * 64 + lane * 16;
                store16_coherent(dst, v);      // h1[t] into row s's h1 half
            }
        }
        if (lane == 0) {
#pragma unroll
            for (int jj = 0; jj < 2; ++jj) {
                out[OUTS + Hn + j0 + jj] = hcur[jj];           // hf layer 1
                out[OUTS + 3 * Hn + j0 + jj] = cst[jj];        // cf layer 1
            }
        }
    }
}

extern "C" void kernel_launch(void* const* d_in, const int* in_sizes, int n_in,
                              void* d_out, int out_size, void* d_ws, size_t ws_size,
                              hipStream_t stream) {
    const float* x        = (const float*)d_in[0];
    const int*   ip       = (const int*)d_in[1];
    const int*   port     = (const int*)d_in[2];
    const float* hidden   = (const float*)d_in[3];
    const float* cell     = (const float*)d_in[4];
    const float* ip_emb   = (const float*)d_in[5];
    const float* port_emb = (const float*)d_in[6];
    const float* Wih0     = (const float*)d_in[7];
    const float* Whh0     = (const float*)d_in[8];
    const float* bih0     = (const float*)d_in[9];
    const float* bhh0     = (const float*)d_in[10];
    const float* Wih1     = (const float*)d_in[11];
    const float* Whh1     = (const float*)d_in[12];
    const float* bih1     = (const float*)d_in[13];
    const float* bhh1     = (const float*)d_in[14];
    float* out = (float*)d_out;

    // ws layout: rowpkt ((Bn+1) x 1024 u64 = 33.6 MB) | xin (4096x33 f32).
    // Tags are s+1 in the high 32 bits; 0xAA poison never matches -> no
    // zeroing pass needed.
    unsigned long long* rowpkt = (unsigned long long*)d_ws;
    float* xin = (float*)(rowpkt + (size_t)(Bn + 1) * ROWP);

    prep_kernel<<<dim3((Bn * INW + 255) / 256), dim3(256), 0, stream>>>(
        x, ip, port, ip_emb, port_emb, xin);

    lstm_kernel<<<dim3(96), dim3(TPB), 0, stream>>>(
        xin, hidden, cell, Wih0, Whh0, bih0, bhh0, Wih1, Whh1, bih1, bhh1,
        out, rowpkt);
}